// Round 16
// baseline (1076.174 us; speedup 1.0000x reference)
//
#include <hip/hip_runtime.h>

#define C  64
#define KK 27
#define BB 4

typedef _Float16 h8 __attribute__((ext_vector_type(8)));
typedef float    f4 __attribute__((ext_vector_type(4)));

// ===================== fast-path ws layout (float offsets) =====================
//      0 : pooled[256]
//    256 : counts[4]
//    260 : gate[256]
//    516 : bnscale[64]
//    580 : bnshift[64]
//   1024 : Wf1[27*4096 halfs]  (55296 floats)
//  56320 : Wf2[27*4096 halfs]  (55296 floats)
// 114688 : xg[(N+1)*64 halfs]
//        : h2[(N+1)*64 halfs]
#define XG_OFF 114688

__global__ __launch_bounds__(256) void init_ws(float* ws) {
  int t = blockIdx.x * 256 + threadIdx.x;
  if (t < 1024) ws[t] = 0.f;
}

// Grid-strided pooling: 16 threads per point row, float4 loads, shuffle+LDS reduce.
__global__ __launch_bounds__(256) void pool_kernel(
    const float4* __restrict__ x4, const int* __restrict__ bidx,
    float* __restrict__ pooled, float* __restrict__ counts, int N)
{
  int t = threadIdx.x;
  int g = t & 15;
  int rowInBlk = t >> 4;
  int lane = t & 63, wv = t >> 6;
  float4 acc[BB];
#pragma unroll
  for (int b = 0; b < BB; ++b) acc[b] = make_float4(0.f, 0.f, 0.f, 0.f);
  int cnt[BB] = {0, 0, 0, 0};
  for (int n = blockIdx.x * 16 + rowInBlk; n < N; n += gridDim.x * 16) {
    int b = bidx[n];
    float4 v = x4[((size_t)n << 4) + g];
    if (b == 0)      { acc[0].x += v.x; acc[0].y += v.y; acc[0].z += v.z; acc[0].w += v.w; }
    else if (b == 1) { acc[1].x += v.x; acc[1].y += v.y; acc[1].z += v.z; acc[1].w += v.w; }
    else if (b == 2) { acc[2].x += v.x; acc[2].y += v.y; acc[2].z += v.z; acc[2].w += v.w; }
    else             { acc[3].x += v.x; acc[3].y += v.y; acc[3].z += v.z; acc[3].w += v.w; }
    if (g == 0) {
      if (b == 0) cnt[0]++; else if (b == 1) cnt[1]++;
      else if (b == 2) cnt[2]++; else cnt[3]++;
    }
  }
#pragma unroll
  for (int b = 0; b < BB; ++b) {
    acc[b].x += __shfl_xor(acc[b].x, 16); acc[b].y += __shfl_xor(acc[b].y, 16);
    acc[b].z += __shfl_xor(acc[b].z, 16); acc[b].w += __shfl_xor(acc[b].w, 16);
    acc[b].x += __shfl_xor(acc[b].x, 32); acc[b].y += __shfl_xor(acc[b].y, 32);
    acc[b].z += __shfl_xor(acc[b].z, 32); acc[b].w += __shfl_xor(acc[b].w, 32);
    cnt[b] += __shfl_xor(cnt[b], 16);
    cnt[b] += __shfl_xor(cnt[b], 32);
  }
  __shared__ float red[4][BB][16][4];
  __shared__ int cred[4][BB];
  if (lane < 16) {
#pragma unroll
    for (int b = 0; b < BB; ++b) {
      red[wv][b][lane][0] = acc[b].x; red[wv][b][lane][1] = acc[b].y;
      red[wv][b][lane][2] = acc[b].z; red[wv][b][lane][3] = acc[b].w;
    }
    if (lane == 0) {
#pragma unroll
      for (int b = 0; b < BB; ++b) cred[wv][b] = cnt[b];
    }
  }
  __syncthreads();
  {
    int b = t >> 6, rem = t & 63;
    int gg = rem >> 2, comp = rem & 3;
    float s = red[0][b][gg][comp] + red[1][b][gg][comp] +
              red[2][b][gg][comp] + red[3][b][gg][comp];
    if (s != 0.f) atomicAdd(&pooled[b * C + (gg << 2) + comp], s);
  }
  if (t < BB) {
    int s = cred[0][t] + cred[1][t] + cred[2][t] + cred[3][t];
    if (s) atomicAdd(&counts[t], (float)s);
  }
}

__global__ __launch_bounds__(256) void gate_kernel(
    const float* __restrict__ pooled, const float* __restrict__ counts,
    const float* __restrict__ w_fc1, const float* __restrict__ b_fc1,
    const float* __restrict__ w_fc2, const float* __restrict__ b_fc2,
    const float* __restrict__ bn_gamma, const float* __restrict__ bn_beta,
    const float* __restrict__ bn_mean, const float* __restrict__ bn_var,
    float* __restrict__ gate, float* __restrict__ bnscale, float* __restrict__ bnshift)
{
  __shared__ float mean[BB * C];
  __shared__ float hh[BB * 16];
  int t = threadIdx.x;
  { int b = t >> 6; mean[t] = pooled[t] / counts[b]; }
  __syncthreads();
  if (t < BB * 16) {
    int b = t >> 4, r = t & 15;
    float s = b_fc1[r];
    for (int c = 0; c < C; ++c) s += mean[b * C + c] * w_fc1[c * 16 + r];
    hh[t] = fmaxf(s, 0.f);
  }
  __syncthreads();
  {
    int b = t >> 6, c = t & 63;
    float s = b_fc2[c];
    for (int r = 0; r < 16; ++r) s += hh[b * 16 + r] * w_fc2[r * 64 + c];
    gate[t] = 1.f / (1.f + expf(-s));
  }
  if (t < C) {
    float sc = bn_gamma[t] * rsqrtf(bn_var[t] + 1e-5f);
    bnscale[t] = sc;
    bnshift[t] = bn_beta[t] - bn_mean[t] * sc;
  }
}

// ---------------- pack W into f16 fragment-major layout; block 54 zeroes row N ----------------
__global__ __launch_bounds__(256) void w_pack(
    const float* __restrict__ W1, const float* __restrict__ W2,
    _Float16* __restrict__ Wf1, _Float16* __restrict__ Wf2,
    _Float16* __restrict__ xg, _Float16* __restrict__ h2, int N)
{
  int kk = blockIdx.x;
  int t = threadIdx.x;
  if (kk == 2 * KK) {          // zero-row maintenance: xg[N], h2[N]
    if (t < 64) {
      xg[((size_t)N << 6) + t] = (_Float16)0.f;
      h2[((size_t)N << 6) + t] = (_Float16)0.f;
    }
    return;
  }
  const float* src = (kk < KK) ? (W1 + ((size_t)kk << 12)) : (W2 + ((size_t)(kk - KK) << 12));
  _Float16* dst = (kk < KK) ? (Wf1 + ((size_t)kk << 12)) : (Wf2 + ((size_t)(kk - KK) << 12));
  for (int e = 0; e < 16; ++e) {
    int idx = e * 256 + t;
    int ci = idx >> 6, co = idx & 63;
    int kt = ci >> 5, i = ci & 7, lh = (ci >> 3) & 3, ct = co >> 4, col = co & 15;
    int lane = lh * 16 + col;
    dst[((kt * 4 + ct) * 64 + lane) * 8 + i] = (_Float16)src[idx];
  }
}

// ---------------- materialize gated feats as f16 ----------------
__global__ __launch_bounds__(256) void xg_pack(
    const float* __restrict__ feats, const int* __restrict__ bidx,
    const float* __restrict__ gate, _Float16* __restrict__ xg, long nchunks)
{
  long i = (long)blockIdx.x * 256 + threadIdx.x;
  long stride = (long)gridDim.x * 256;
  for (; i < nchunks; i += stride) {
    long row = i >> 3; int c8 = (int)(i & 7) << 3;
    const float* x = feats + (row << 6) + c8;
    const float* g = gate + ((size_t)(bidx[row]) << 6) + c8;
    float4 v0 = *(const float4*)x;
    float4 v1 = *(const float4*)(x + 4);
    float4 g0 = *(const float4*)g;
    float4 g1 = *(const float4*)(g + 4);
    h8 o;
    o[0] = (_Float16)(v0.x * g0.x); o[1] = (_Float16)(v0.y * g0.y);
    o[2] = (_Float16)(v0.z * g0.z); o[3] = (_Float16)(v0.w * g0.w);
    o[4] = (_Float16)(v1.x * g1.x); o[5] = (_Float16)(v1.y * g1.y);
    o[6] = (_Float16)(v1.z * g1.z); o[7] = (_Float16)(v1.w * g1.w);
    *(h8*)(xg + (row << 6) + c8) = o;
  }
}

// ---------------- fused sparse-conv: dense-27 straight-line MFMA, 32 rows/wave ----------------
// All control flow removed from the k-loop: invalid (k,lane) pairs gather the
// zeroed row N (exact zero contribution); full static unroll lets the compiler
// software-pipeline gathers 4-5 iterations deep with counted vmcnt.
// MODE 0: conv1 — src = xg, epilogue BN+ReLU -> h2 (f16)
// MODE 1: conv2 — src = h2, epilogue +bias -> out (f32)
template <int MODE>
__global__ __launch_bounds__(256, 4) void conv_fused(
    const _Float16* __restrict__ src, const _Float16* __restrict__ Wf,
    const int* __restrict__ nbr, const float* __restrict__ epA,
    const float* __restrict__ epB, _Float16* __restrict__ outh,
    float* __restrict__ outf, int N)
{
  int t = threadIdx.x, wv = t >> 6, lane = t & 63;
  int rbase = blockIdx.x * 128 + (wv << 5);
  int row0 = rbase + (lane & 15);
  int row1 = row0 + 16;
  int rc0 = min(row0, N - 1);
  int rc1 = min(row1, N - 1);
  bool inb0 = row0 < N, inb1 = row1 < N;
  int koff = (lane >> 4) << 3;

  f4 acc0[4], acc1[4];
#pragma unroll
  for (int ct = 0; ct < 4; ++ct) { acc0[ct] = (f4){0,0,0,0}; acc1[ct] = (f4){0,0,0,0}; }

#pragma unroll
  for (int k = 0; k < KK; ++k) {
    int v0 = nbr[(size_t)k * N + rc0];
    int v1 = nbr[(size_t)k * N + rc1];
    int s0 = (inb0 && v0 >= 0) ? v0 : N;
    int s1 = (inb1 && v1 >= 0) ? v1 : N;
    const _Float16* p0 = src + ((size_t)s0 << 6) + koff;
    const _Float16* p1 = src + ((size_t)s1 << 6) + koff;
    h8 a0 = *(const h8*)p0;
    h8 a0h = *(const h8*)(p0 + 32);
    h8 a1 = *(const h8*)p1;
    h8 a1h = *(const h8*)(p1 + 32);
    const h8* Wb = (const h8*)(Wf + ((size_t)k << 12));
#pragma unroll
    for (int ct = 0; ct < 4; ++ct) {
      h8 w0 = Wb[ct * 64 + lane];
      h8 w1 = Wb[(4 + ct) * 64 + lane];
      acc0[ct] = __builtin_amdgcn_mfma_f32_16x16x32_f16(a0,  w0, acc0[ct], 0, 0, 0);
      acc0[ct] = __builtin_amdgcn_mfma_f32_16x16x32_f16(a0h, w1, acc0[ct], 0, 0, 0);
      acc1[ct] = __builtin_amdgcn_mfma_f32_16x16x32_f16(a1,  w0, acc1[ct], 0, 0, 0);
      acc1[ct] = __builtin_amdgcn_mfma_f32_16x16x32_f16(a1h, w1, acc1[ct], 0, 0, 0);
    }
  }

  // C/D: row = grpbase + (lane>>4)*4 + rg, col = ct*16 + (lane&15)
  int rsub = (lane >> 4) << 2;
  int ocol = lane & 15;
#pragma unroll
  for (int g = 0; g < 2; ++g) {
    int obase = rbase + g * 16 + rsub;
    f4* accp = g ? acc1 : acc0;
#pragma unroll
    for (int ct = 0; ct < 4; ++ct) {
      int col = ct * 16 + ocol;
      float ea = (MODE == 0) ? epA[col] : 0.f;
      float eb = epB[col];
#pragma unroll
      for (int rg = 0; rg < 4; ++rg) {
        int r = obase + rg;
        if (r < N) {
          if (MODE == 0) {
            float v = fmaxf(fmaf(accp[ct][rg], ea, eb), 0.f);
            outh[((size_t)r << 6) + col] = (_Float16)v;
          } else {
            outf[((size_t)r << 6) + col] = accp[ct][rg] + eb;
          }
        }
      }
    }
  }
}

// ---------------- round-1 fallback (small ws) ----------------
__global__ __launch_bounds__(256) void scale_w1(
    const float* __restrict__ w1, const float* __restrict__ gate,
    float* __restrict__ w1g)
{
  int b = blockIdx.x & 3, k = blockIdx.x >> 2;
  const float* src = w1 + ((size_t)k << 12);
  float* dst = w1g + (((size_t)(b * KK + k)) << 12);
  const float* g = gate + (b << 6);
  for (int it = 0; it < 16; ++it) {
    int pos = it * 256 + threadIdx.x;
    int ci = pos >> 6;
    dst[pos] = g[ci] * src[pos];
  }
}

template <int MODE>
__global__ __launch_bounds__(256) void spconv_kernel(
    const float* __restrict__ x, const int* __restrict__ nbr,
    const int* __restrict__ bidx, const float* __restrict__ W,
    const float* __restrict__ ep_a, const float* __restrict__ ep_b,
    float* __restrict__ out, int N)
{
  int wid = (int)((blockIdx.x * 256u + threadIdx.x) >> 6);
  if (wid >= N) return;
  int lane = threadIdx.x & 63;
  int n = __builtin_amdgcn_readfirstlane(wid);
  const float* Wb = W;
  if (MODE == 0) {
    int b = __builtin_amdgcn_readfirstlane(bidx[n]);
    Wb += (size_t)b * (KK * C * C);
  }
  float acc = 0.f;
#pragma unroll 1
  for (int k = 0; k < KK; ++k) {
    int idx = __builtin_amdgcn_readfirstlane(nbr[(size_t)k * N + n]);
    if (idx < 0) continue;
    const float* xr = x + ((size_t)idx << 6);
    const float* wr = Wb + (k << 12) + lane;
#pragma unroll
    for (int ci = 0; ci < C; ++ci) acc = fmaf(xr[ci], wr[ci << 6], acc);
  }
  float r;
  if (MODE == 0) r = fmaxf(fmaf(acc, ep_a[lane], ep_b[lane]), 0.f);
  else           r = acc + ep_b[lane];
  out[((size_t)n << 6) + lane] = r;
}

extern "C" void kernel_launch(void* const* d_in, const int* in_sizes, int n_in,
                              void* d_out, int out_size, void* d_ws, size_t ws_size,
                              hipStream_t stream) {
  const float* feats   = (const float*)d_in[0];
  const int*   nbr     = (const int*)  d_in[1];
  const int*   bidx    = (const int*)  d_in[2];
  const float* w_fc1   = (const float*)d_in[3];
  const float* b_fc1   = (const float*)d_in[4];
  const float* w_fc2   = (const float*)d_in[5];
  const float* b_fc2   = (const float*)d_in[6];
  const float* w_conv1 = (const float*)d_in[7];
  const float* bn_gamma= (const float*)d_in[8];
  const float* bn_beta = (const float*)d_in[9];
  const float* bn_mean = (const float*)d_in[10];
  const float* bn_var  = (const float*)d_in[11];
  const float* w_conv2 = (const float*)d_in[12];
  const float* b_conv2 = (const float*)d_in[13];

  int N = in_sizes[0] / C;
  float* ws      = (float*)d_ws;
  float* pooled  = ws;
  float* counts  = ws + 256;
  float* gate    = ws + 260;
  float* bnscale = ws + 516;
  float* bnshift = ws + 580;
  float* out     = (float*)d_out;

  size_t need = ((size_t)XG_OFF + ((size_t)N + 1) * 64) * 4ull;   // Wf + xg + h2 (N+1 rows each)

  if (ws_size >= need) {
    _Float16* Wf1 = (_Float16*)(ws + 1024);
    _Float16* Wf2 = (_Float16*)(ws + 56320);
    _Float16* xg  = (_Float16*)(ws + XG_OFF);
    _Float16* h2  = (_Float16*)(ws + XG_OFF + ((size_t)N + 1) * 32);

    hipLaunchKernelGGL(init_ws, dim3(4), dim3(256), 0, stream, ws);
    hipLaunchKernelGGL(pool_kernel, dim3(1024), dim3(256), 0, stream,
                       (const float4*)feats, bidx, pooled, counts, N);
    hipLaunchKernelGGL(gate_kernel, dim3(1), dim3(256), 0, stream,
                       pooled, counts, w_fc1, b_fc1, w_fc2, b_fc2,
                       bn_gamma, bn_beta, bn_mean, bn_var, gate, bnscale, bnshift);
    hipLaunchKernelGGL(w_pack, dim3(2 * KK + 1), dim3(256), 0, stream,
                       w_conv1, w_conv2, Wf1, Wf2, xg, h2, N);
    hipLaunchKernelGGL(xg_pack, dim3(2048), dim3(256), 0, stream,
                       feats, bidx, gate, xg, (long)N * 8);
    // conv1: dense-27 gather-MFMA, BN+ReLU -> h2 (f16)
    hipLaunchKernelGGL((conv_fused<0>), dim3((N + 127) / 128), dim3(256), 0, stream,
                       xg, Wf1, nbr, bnscale, bnshift, h2, nullptr, N);
    // conv2: dense-27 gather-MFMA, +bias -> out (f32)
    hipLaunchKernelGGL((conv_fused<1>), dim3((N + 127) / 128), dim3(256), 0, stream,
                       h2, Wf2, nbr, nullptr, b_conv2, nullptr, out, N);
  } else {
    // round-1 fallback path
    float* w1g = ws + 1024;
    float* h   = ws + 1024 + BB * KK * C * C;
    hipLaunchKernelGGL(init_ws, dim3(4), dim3(256), 0, stream, ws);
    hipLaunchKernelGGL(pool_kernel, dim3(1024), dim3(256), 0, stream,
                       (const float4*)feats, bidx, pooled, counts, N);
    hipLaunchKernelGGL(gate_kernel, dim3(1), dim3(256), 0, stream,
                       pooled, counts, w_fc1, b_fc1, w_fc2, b_fc2,
                       bn_gamma, bn_beta, bn_mean, bn_var, gate, bnscale, bnshift);
    hipLaunchKernelGGL(scale_w1, dim3(KK * BB), dim3(256), 0, stream,
                       w_conv1, gate, w1g);
    hipLaunchKernelGGL((spconv_kernel<0>), dim3((N + 3) / 4), dim3(256), 0, stream,
                       feats, nbr, bidx, w1g, bnscale, bnshift, h, N);
    hipLaunchKernelGGL((spconv_kernel<1>), dim3((N + 3) / 4), dim3(256), 0, stream,
                       h, nbr, bidx, w_conv2, nullptr, b_conv2, out, N);
  }
}

// Round 17
// 1055.612 us; speedup vs baseline: 1.0195x; 1.0195x over previous
//
#include <hip/hip_runtime.h>

#define C  64
#define KK 27
#define BB 4

typedef _Float16 h8 __attribute__((ext_vector_type(8)));
typedef float    f4 __attribute__((ext_vector_type(4)));

// ===================== fast-path ws layout (float offsets) =====================
//      0 : pooled[256]
//    256 : counts[4]
//    260 : gate[256]
//    516 : bnscale[64]
//    580 : bnshift[64]
//   1024 : Wf1[27*4096 halfs]  (55296 floats)
//  56320 : Wf2[27*4096 halfs]  (55296 floats)
// 114688 : xg[(N+1)*64 halfs]
//        : h2[(N+1)*64 halfs]
#define XG_OFF 114688

__global__ __launch_bounds__(256) void init_ws(float* ws) {
  int t = blockIdx.x * 256 + threadIdx.x;
  if (t < 1024) ws[t] = 0.f;
}

// Grid-strided pooling: 16 threads per point row, float4 loads, shuffle+LDS reduce.
__global__ __launch_bounds__(256) void pool_kernel(
    const float4* __restrict__ x4, const int* __restrict__ bidx,
    float* __restrict__ pooled, float* __restrict__ counts, int N)
{
  int t = threadIdx.x;
  int g = t & 15;
  int rowInBlk = t >> 4;
  int lane = t & 63, wv = t >> 6;
  float4 acc[BB];
#pragma unroll
  for (int b = 0; b < BB; ++b) acc[b] = make_float4(0.f, 0.f, 0.f, 0.f);
  int cnt[BB] = {0, 0, 0, 0};
  for (int n = blockIdx.x * 16 + rowInBlk; n < N; n += gridDim.x * 16) {
    int b = bidx[n];
    float4 v = x4[((size_t)n << 4) + g];
    if (b == 0)      { acc[0].x += v.x; acc[0].y += v.y; acc[0].z += v.z; acc[0].w += v.w; }
    else if (b == 1) { acc[1].x += v.x; acc[1].y += v.y; acc[1].z += v.z; acc[1].w += v.w; }
    else if (b == 2) { acc[2].x += v.x; acc[2].y += v.y; acc[2].z += v.z; acc[2].w += v.w; }
    else             { acc[3].x += v.x; acc[3].y += v.y; acc[3].z += v.z; acc[3].w += v.w; }
    if (g == 0) {
      if (b == 0) cnt[0]++; else if (b == 1) cnt[1]++;
      else if (b == 2) cnt[2]++; else cnt[3]++;
    }
  }
#pragma unroll
  for (int b = 0; b < BB; ++b) {
    acc[b].x += __shfl_xor(acc[b].x, 16); acc[b].y += __shfl_xor(acc[b].y, 16);
    acc[b].z += __shfl_xor(acc[b].z, 16); acc[b].w += __shfl_xor(acc[b].w, 16);
    acc[b].x += __shfl_xor(acc[b].x, 32); acc[b].y += __shfl_xor(acc[b].y, 32);
    acc[b].z += __shfl_xor(acc[b].z, 32); acc[b].w += __shfl_xor(acc[b].w, 32);
    cnt[b] += __shfl_xor(cnt[b], 16);
    cnt[b] += __shfl_xor(cnt[b], 32);
  }
  __shared__ float red[4][BB][16][4];
  __shared__ int cred[4][BB];
  if (lane < 16) {
#pragma unroll
    for (int b = 0; b < BB; ++b) {
      red[wv][b][lane][0] = acc[b].x; red[wv][b][lane][1] = acc[b].y;
      red[wv][b][lane][2] = acc[b].z; red[wv][b][lane][3] = acc[b].w;
    }
    if (lane == 0) {
#pragma unroll
      for (int b = 0; b < BB; ++b) cred[wv][b] = cnt[b];
    }
  }
  __syncthreads();
  {
    int b = t >> 6, rem = t & 63;
    int gg = rem >> 2, comp = rem & 3;
    float s = red[0][b][gg][comp] + red[1][b][gg][comp] +
              red[2][b][gg][comp] + red[3][b][gg][comp];
    if (s != 0.f) atomicAdd(&pooled[b * C + (gg << 2) + comp], s);
  }
  if (t < BB) {
    int s = cred[0][t] + cred[1][t] + cred[2][t] + cred[3][t];
    if (s) atomicAdd(&counts[t], (float)s);
  }
}

__global__ __launch_bounds__(256) void gate_kernel(
    const float* __restrict__ pooled, const float* __restrict__ counts,
    const float* __restrict__ w_fc1, const float* __restrict__ b_fc1,
    const float* __restrict__ w_fc2, const float* __restrict__ b_fc2,
    const float* __restrict__ bn_gamma, const float* __restrict__ bn_beta,
    const float* __restrict__ bn_mean, const float* __restrict__ bn_var,
    float* __restrict__ gate, float* __restrict__ bnscale, float* __restrict__ bnshift)
{
  __shared__ float mean[BB * C];
  __shared__ float hh[BB * 16];
  int t = threadIdx.x;
  { int b = t >> 6; mean[t] = pooled[t] / counts[b]; }
  __syncthreads();
  if (t < BB * 16) {
    int b = t >> 4, r = t & 15;
    float s = b_fc1[r];
    for (int c = 0; c < C; ++c) s += mean[b * C + c] * w_fc1[c * 16 + r];
    hh[t] = fmaxf(s, 0.f);
  }
  __syncthreads();
  {
    int b = t >> 6, c = t & 63;
    float s = b_fc2[c];
    for (int r = 0; r < 16; ++r) s += hh[b * 16 + r] * w_fc2[r * 64 + c];
    gate[t] = 1.f / (1.f + expf(-s));
  }
  if (t < C) {
    float sc = bn_gamma[t] * rsqrtf(bn_var[t] + 1e-5f);
    bnscale[t] = sc;
    bnshift[t] = bn_beta[t] - bn_mean[t] * sc;
  }
}

// ---------------- pack W into f16 fragment-major layout; block 54 zeroes row N ----------------
__global__ __launch_bounds__(256) void w_pack(
    const float* __restrict__ W1, const float* __restrict__ W2,
    _Float16* __restrict__ Wf1, _Float16* __restrict__ Wf2,
    _Float16* __restrict__ xg, _Float16* __restrict__ h2, int N)
{
  int kk = blockIdx.x;
  int t = threadIdx.x;
  if (kk == 2 * KK) {          // zero-row maintenance: xg[N], h2[N]
    if (t < 64) {
      xg[((size_t)N << 6) + t] = (_Float16)0.f;
      h2[((size_t)N << 6) + t] = (_Float16)0.f;
    }
    return;
  }
  const float* src = (kk < KK) ? (W1 + ((size_t)kk << 12)) : (W2 + ((size_t)(kk - KK) << 12));
  _Float16* dst = (kk < KK) ? (Wf1 + ((size_t)kk << 12)) : (Wf2 + ((size_t)(kk - KK) << 12));
  for (int e = 0; e < 16; ++e) {
    int idx = e * 256 + t;
    int ci = idx >> 6, co = idx & 63;
    int kt = ci >> 5, i = ci & 7, lh = (ci >> 3) & 3, ct = co >> 4, col = co & 15;
    int lane = lh * 16 + col;
    dst[((kt * 4 + ct) * 64 + lane) * 8 + i] = (_Float16)src[idx];
  }
}

// ---------------- materialize gated feats as f16 ----------------
__global__ __launch_bounds__(256) void xg_pack(
    const float* __restrict__ feats, const int* __restrict__ bidx,
    const float* __restrict__ gate, _Float16* __restrict__ xg, long nchunks)
{
  long i = (long)blockIdx.x * 256 + threadIdx.x;
  long stride = (long)gridDim.x * 256;
  for (; i < nchunks; i += stride) {
    long row = i >> 3; int c8 = (int)(i & 7) << 3;
    const float* x = feats + (row << 6) + c8;
    const float* g = gate + ((size_t)(bidx[row]) << 6) + c8;
    float4 v0 = *(const float4*)x;
    float4 v1 = *(const float4*)(x + 4);
    float4 g0 = *(const float4*)g;
    float4 g1 = *(const float4*)(g + 4);
    h8 o;
    o[0] = (_Float16)(v0.x * g0.x); o[1] = (_Float16)(v0.y * g0.y);
    o[2] = (_Float16)(v0.z * g0.z); o[3] = (_Float16)(v0.w * g0.w);
    o[4] = (_Float16)(v1.x * g1.x); o[5] = (_Float16)(v1.y * g1.y);
    o[6] = (_Float16)(v1.z * g1.z); o[7] = (_Float16)(v1.w * g1.w);
    *(h8*)(xg + (row << 6) + c8) = o;
  }
}

// ---------------- fused sparse-conv: sparse k-walk, branchless body, 2-deep rotation ----------------
// Union active-k mask walked ~18x; body has NO internal branches: invalid lanes/groups
// gather the zeroed row N (exact +0), all 16 MFMAs unconditional. Explicit c/n/p
// register-set rotation keeps ~12 gathers in flight regardless of scheduler policy.
// MODE 0: conv1 — src = xg, epilogue BN+ReLU -> h2 (f16)
// MODE 1: conv2 — src = h2, epilogue +bias -> out (f32)
template <int MODE>
__global__ __launch_bounds__(256, 3) void conv_fused(
    const _Float16* __restrict__ src, const _Float16* __restrict__ Wf,
    const int* __restrict__ nbr, const float* __restrict__ epA,
    const float* __restrict__ epB, _Float16* __restrict__ outh,
    float* __restrict__ outf, int N)
{
  int t = threadIdx.x, wv = t >> 6, lane = t & 63;
  int rbase = blockIdx.x * 128 + (wv << 5);
  int row0 = rbase + (lane & 15);
  int row1 = row0 + 16;
  int rc0 = min(row0, N - 1);
  int rc1 = min(row1, N - 1);
  bool inb0 = row0 < N, inb1 = row1 < N;
  int koff = (lane >> 4) << 3;

  // ---- Phase 1: union active-k mask (wave-uniform), warms nbr in L1 ----
  unsigned am = 0;
#pragma unroll
  for (int k = 0; k < KK; ++k) {
    int v0 = nbr[(size_t)k * N + rc0];
    int v1 = nbr[(size_t)k * N + rc1];
    bool any = (inb0 && v0 >= 0) || (inb1 && v1 >= 0);
    if (__ballot(any) != 0ull) am |= (1u << k);
  }
  am = __builtin_amdgcn_readfirstlane(am);

  f4 acc0[4], acc1[4];
#pragma unroll
  for (int ct = 0; ct < 4; ++ct) { acc0[ct] = (f4){0,0,0,0}; acc1[ct] = (f4){0,0,0,0}; }

  // Unconditional gather set: invalid (k,lane) reads zeroed row N (L1-hot).
  auto GSET = [&](int kv, h8& g0a, h8& g0b, h8& g1a, h8& g1b) {
    int kc = kv < 0 ? 0 : kv;
    int v0 = nbr[(size_t)kc * N + rc0];      // L1-hot (phase-1 warmed)
    int v1 = nbr[(size_t)kc * N + rc1];
    int s0 = (kv >= 0 && inb0 && v0 >= 0) ? v0 : N;
    int s1 = (kv >= 0 && inb1 && v1 >= 0) ? v1 : N;
    const _Float16* p0 = src + ((size_t)s0 << 6) + koff;
    const _Float16* p1 = src + ((size_t)s1 << 6) + koff;
    g0a = *(const h8*)p0; g0b = *(const h8*)(p0 + 32);
    g1a = *(const h8*)p1; g1b = *(const h8*)(p1 + 32);
  };

  unsigned m = am;
  int k0 = m ? (int)__builtin_ctz(m) : -1; if (k0 >= 0) m &= m - 1;
  int k1 = m ? (int)__builtin_ctz(m) : -1; if (k1 >= 0) m &= m - 1;
  int k2 = m ? (int)__builtin_ctz(m) : -1; if (k2 >= 0) m &= m - 1;
  h8 c0a, c0b, c1a, c1b;      // compute set (k0)
  h8 n0a, n0b, n1a, n1b;      // next set (k1)
  h8 p0a, p0b, p1a, p1b;      // prefetch set (k2)
  GSET(k0, c0a, c0b, c1a, c1b);
  GSET(k1, n0a, n0b, n1a, n1b);
  while (k0 >= 0) {
    GSET(k2, p0a, p0b, p1a, p1b);            // 2-ahead gathers in flight
    const h8* Wb = (const h8*)(Wf + ((size_t)(k0 < 0 ? 0 : k0) << 12));
#pragma unroll
    for (int ct = 0; ct < 4; ++ct) {
      h8 w0 = Wb[ct * 64 + lane];
      h8 w1 = Wb[(4 + ct) * 64 + lane];
      acc0[ct] = __builtin_amdgcn_mfma_f32_16x16x32_f16(c0a, w0, acc0[ct], 0, 0, 0);
      acc0[ct] = __builtin_amdgcn_mfma_f32_16x16x32_f16(c0b, w1, acc0[ct], 0, 0, 0);
      acc1[ct] = __builtin_amdgcn_mfma_f32_16x16x32_f16(c1a, w0, acc1[ct], 0, 0, 0);
      acc1[ct] = __builtin_amdgcn_mfma_f32_16x16x32_f16(c1b, w1, acc1[ct], 0, 0, 0);
    }
    c0a = n0a; c0b = n0b; c1a = n1a; c1b = n1b;
    n0a = p0a; n0b = p0b; n1a = p1a; n1b = p1b;
    k0 = k1; k1 = k2;
    k2 = m ? (int)__builtin_ctz(m) : -1; if (k2 >= 0) m &= m - 1;
  }

  // C/D: row = grpbase + (lane>>4)*4 + rg, col = ct*16 + (lane&15)
  int rsub = (lane >> 4) << 2;
  int ocol = lane & 15;
#pragma unroll
  for (int g = 0; g < 2; ++g) {
    int obase = rbase + g * 16 + rsub;
    f4* accp = g ? acc1 : acc0;
#pragma unroll
    for (int ct = 0; ct < 4; ++ct) {
      int col = ct * 16 + ocol;
      float ea = (MODE == 0) ? epA[col] : 0.f;
      float eb = epB[col];
#pragma unroll
      for (int rg = 0; rg < 4; ++rg) {
        int r = obase + rg;
        if (r < N) {
          if (MODE == 0) {
            float v = fmaxf(fmaf(accp[ct][rg], ea, eb), 0.f);
            outh[((size_t)r << 6) + col] = (_Float16)v;
          } else {
            outf[((size_t)r << 6) + col] = accp[ct][rg] + eb;
          }
        }
      }
    }
  }
}

// ---------------- round-1 fallback (small ws) ----------------
__global__ __launch_bounds__(256) void scale_w1(
    const float* __restrict__ w1, const float* __restrict__ gate,
    float* __restrict__ w1g)
{
  int b = blockIdx.x & 3, k = blockIdx.x >> 2;
  const float* src = w1 + ((size_t)k << 12);
  float* dst = w1g + (((size_t)(b * KK + k)) << 12);
  const float* g = gate + (b << 6);
  for (int it = 0; it < 16; ++it) {
    int pos = it * 256 + threadIdx.x;
    int ci = pos >> 6;
    dst[pos] = g[ci] * src[pos];
  }
}

template <int MODE>
__global__ __launch_bounds__(256) void spconv_kernel(
    const float* __restrict__ x, const int* __restrict__ nbr,
    const int* __restrict__ bidx, const float* __restrict__ W,
    const float* __restrict__ ep_a, const float* __restrict__ ep_b,
    float* __restrict__ out, int N)
{
  int wid = (int)((blockIdx.x * 256u + threadIdx.x) >> 6);
  if (wid >= N) return;
  int lane = threadIdx.x & 63;
  int n = __builtin_amdgcn_readfirstlane(wid);
  const float* Wb = W;
  if (MODE == 0) {
    int b = __builtin_amdgcn_readfirstlane(bidx[n]);
    Wb += (size_t)b * (KK * C * C);
  }
  float acc = 0.f;
#pragma unroll 1
  for (int k = 0; k < KK; ++k) {
    int idx = __builtin_amdgcn_readfirstlane(nbr[(size_t)k * N + n]);
    if (idx < 0) continue;
    const float* xr = x + ((size_t)idx << 6);
    const float* wr = Wb + (k << 12) + lane;
#pragma unroll
    for (int ci = 0; ci < C; ++ci) acc = fmaf(xr[ci], wr[ci << 6], acc);
  }
  float r;
  if (MODE == 0) r = fmaxf(fmaf(acc, ep_a[lane], ep_b[lane]), 0.f);
  else           r = acc + ep_b[lane];
  out[((size_t)n << 6) + lane] = r;
}

extern "C" void kernel_launch(void* const* d_in, const int* in_sizes, int n_in,
                              void* d_out, int out_size, void* d_ws, size_t ws_size,
                              hipStream_t stream) {
  const float* feats   = (const float*)d_in[0];
  const int*   nbr     = (const int*)  d_in[1];
  const int*   bidx    = (const int*)  d_in[2];
  const float* w_fc1   = (const float*)d_in[3];
  const float* b_fc1   = (const float*)d_in[4];
  const float* w_fc2   = (const float*)d_in[5];
  const float* b_fc2   = (const float*)d_in[6];
  const float* w_conv1 = (const float*)d_in[7];
  const float* bn_gamma= (const float*)d_in[8];
  const float* bn_beta = (const float*)d_in[9];
  const float* bn_mean = (const float*)d_in[10];
  const float* bn_var  = (const float*)d_in[11];
  const float* w_conv2 = (const float*)d_in[12];
  const float* b_conv2 = (const float*)d_in[13];

  int N = in_sizes[0] / C;
  float* ws      = (float*)d_ws;
  float* pooled  = ws;
  float* counts  = ws + 256;
  float* gate    = ws + 260;
  float* bnscale = ws + 516;
  float* bnshift = ws + 580;
  float* out     = (float*)d_out;

  size_t need = ((size_t)XG_OFF + ((size_t)N + 1) * 64) * 4ull;   // Wf + xg + h2 (N+1 rows each)

  if (ws_size >= need) {
    _Float16* Wf1 = (_Float16*)(ws + 1024);
    _Float16* Wf2 = (_Float16*)(ws + 56320);
    _Float16* xg  = (_Float16*)(ws + XG_OFF);
    _Float16* h2  = (_Float16*)(ws + XG_OFF + ((size_t)N + 1) * 32);

    hipLaunchKernelGGL(init_ws, dim3(4), dim3(256), 0, stream, ws);
    hipLaunchKernelGGL(pool_kernel, dim3(1024), dim3(256), 0, stream,
                       (const float4*)feats, bidx, pooled, counts, N);
    hipLaunchKernelGGL(gate_kernel, dim3(1), dim3(256), 0, stream,
                       pooled, counts, w_fc1, b_fc1, w_fc2, b_fc2,
                       bn_gamma, bn_beta, bn_mean, bn_var, gate, bnscale, bnshift);
    hipLaunchKernelGGL(w_pack, dim3(2 * KK + 1), dim3(256), 0, stream,
                       w_conv1, w_conv2, Wf1, Wf2, xg, h2, N);
    hipLaunchKernelGGL(xg_pack, dim3(2048), dim3(256), 0, stream,
                       feats, bidx, gate, xg, (long)N * 8);
    // conv1: sparse-walk gather-MFMA, BN+ReLU -> h2 (f16)
    hipLaunchKernelGGL((conv_fused<0>), dim3((N + 127) / 128), dim3(256), 0, stream,
                       xg, Wf1, nbr, bnscale, bnshift, h2, nullptr, N);
    // conv2: sparse-walk gather-MFMA, +bias -> out (f32)
    hipLaunchKernelGGL((conv_fused<1>), dim3((N + 127) / 128), dim3(256), 0, stream,
                       h2, Wf2, nbr, nullptr, b_conv2, nullptr, out, N);
  } else {
    // round-1 fallback path
    float* w1g = ws + 1024;
    float* h   = ws + 1024 + BB * KK * C * C;
    hipLaunchKernelGGL(init_ws, dim3(4), dim3(256), 0, stream, ws);
    hipLaunchKernelGGL(pool_kernel, dim3(1024), dim3(256), 0, stream,
                       (const float4*)feats, bidx, pooled, counts, N);
    hipLaunchKernelGGL(gate_kernel, dim3(1), dim3(256), 0, stream,
                       pooled, counts, w_fc1, b_fc1, w_fc2, b_fc2,
                       bn_gamma, bn_beta, bn_mean, bn_var, gate, bnscale, bnshift);
    hipLaunchKernelGGL(scale_w1, dim3(KK * BB), dim3(256), 0, stream,
                       w_conv1, gate, w1g);
    hipLaunchKernelGGL((spconv_kernel<0>), dim3((N + 3) / 4), dim3(256), 0, stream,
                       feats, nbr, bidx, w1g, bnscale, bnshift, h, N);
    hipLaunchKernelGGL((spconv_kernel<1>), dim3((N + 3) / 4), dim3(256), 0, stream,
                       h, nbr, bidx, w_conv2, nullptr, b_conv2, out, N);
  }
}

// Round 18
// 733.022 us; speedup vs baseline: 1.4681x; 1.4401x over previous
//
#include <hip/hip_runtime.h>

#define C  64
#define KK 27
#define BB 4

typedef _Float16 h4 __attribute__((ext_vector_type(4)));
typedef _Float16 h8 __attribute__((ext_vector_type(8)));
typedef float    f4 __attribute__((ext_vector_type(4)));

// ===================== fast-path ws layout (float offsets) =====================
//      0 : pooled[256]
//    256 : counts[4]
//    260 : gate[256]
//    516 : bnscale[64]
//    580 : bnshift[64]
//    698 : cursor[26] (int)
//   1024 : Wf1[27*4096 halfs]  (55296 floats)
//  56320 : Wf2[27*4096 halfs]  (55296 floats)
// 114688 : pairs[NJ*KSTRIDE*2] (int)
// H_OFF  : h[N*C] (f32)
#define KSTRIDE  40960
#define SEGPK    (KSTRIDE / 128)
#define NJ       26
#define PAIRS_OFF 114688
#define H_OFF    (PAIRS_OFF + 2 * NJ * KSTRIDE)

__global__ __launch_bounds__(256) void init_ws(float* ws) {
  int t = blockIdx.x * 256 + threadIdx.x;
  if (t < 1024) ws[t] = 0.f;
}

// Grid-strided pooling: 16 threads per point row, float4 loads, shuffle+LDS reduce.
__global__ __launch_bounds__(256) void pool_kernel(
    const float4* __restrict__ x4, const int* __restrict__ bidx,
    float* __restrict__ pooled, float* __restrict__ counts, int N)
{
  int t = threadIdx.x;
  int g = t & 15;
  int rowInBlk = t >> 4;
  int lane = t & 63, wv = t >> 6;
  float4 acc[BB];
#pragma unroll
  for (int b = 0; b < BB; ++b) acc[b] = make_float4(0.f, 0.f, 0.f, 0.f);
  int cnt[BB] = {0, 0, 0, 0};
  for (int n = blockIdx.x * 16 + rowInBlk; n < N; n += gridDim.x * 16) {
    int b = bidx[n];
    float4 v = x4[((size_t)n << 4) + g];
    if (b == 0)      { acc[0].x += v.x; acc[0].y += v.y; acc[0].z += v.z; acc[0].w += v.w; }
    else if (b == 1) { acc[1].x += v.x; acc[1].y += v.y; acc[1].z += v.z; acc[1].w += v.w; }
    else if (b == 2) { acc[2].x += v.x; acc[2].y += v.y; acc[2].z += v.z; acc[2].w += v.w; }
    else             { acc[3].x += v.x; acc[3].y += v.y; acc[3].z += v.z; acc[3].w += v.w; }
    if (g == 0) {
      if (b == 0) cnt[0]++; else if (b == 1) cnt[1]++;
      else if (b == 2) cnt[2]++; else cnt[3]++;
    }
  }
#pragma unroll
  for (int b = 0; b < BB; ++b) {
    acc[b].x += __shfl_xor(acc[b].x, 16); acc[b].y += __shfl_xor(acc[b].y, 16);
    acc[b].z += __shfl_xor(acc[b].z, 16); acc[b].w += __shfl_xor(acc[b].w, 16);
    acc[b].x += __shfl_xor(acc[b].x, 32); acc[b].y += __shfl_xor(acc[b].y, 32);
    acc[b].z += __shfl_xor(acc[b].z, 32); acc[b].w += __shfl_xor(acc[b].w, 32);
    cnt[b] += __shfl_xor(cnt[b], 16);
    cnt[b] += __shfl_xor(cnt[b], 32);
  }
  __shared__ float red[4][BB][16][4];
  __shared__ int cred[4][BB];
  if (lane < 16) {
#pragma unroll
    for (int b = 0; b < BB; ++b) {
      red[wv][b][lane][0] = acc[b].x; red[wv][b][lane][1] = acc[b].y;
      red[wv][b][lane][2] = acc[b].z; red[wv][b][lane][3] = acc[b].w;
    }
    if (lane == 0) {
#pragma unroll
      for (int b = 0; b < BB; ++b) cred[wv][b] = cnt[b];
    }
  }
  __syncthreads();
  {
    int b = t >> 6, rem = t & 63;
    int gg = rem >> 2, comp = rem & 3;
    float s = red[0][b][gg][comp] + red[1][b][gg][comp] +
              red[2][b][gg][comp] + red[3][b][gg][comp];
    if (s != 0.f) atomicAdd(&pooled[b * C + (gg << 2) + comp], s);
  }
  if (t < BB) {
    int s = cred[0][t] + cred[1][t] + cred[2][t] + cred[3][t];
    if (s) atomicAdd(&counts[t], (float)s);
  }
}

__global__ __launch_bounds__(256) void gate_kernel(
    const float* __restrict__ pooled, const float* __restrict__ counts,
    const float* __restrict__ w_fc1, const float* __restrict__ b_fc1,
    const float* __restrict__ w_fc2, const float* __restrict__ b_fc2,
    const float* __restrict__ bn_gamma, const float* __restrict__ bn_beta,
    const float* __restrict__ bn_mean, const float* __restrict__ bn_var,
    float* __restrict__ gate, float* __restrict__ bnscale, float* __restrict__ bnshift)
{
  __shared__ float mean[BB * C];
  __shared__ float hh[BB * 16];
  int t = threadIdx.x;
  { int b = t >> 6; mean[t] = pooled[t] / counts[b]; }
  __syncthreads();
  if (t < BB * 16) {
    int b = t >> 4, r = t & 15;
    float s = b_fc1[r];
    for (int c = 0; c < C; ++c) s += mean[b * C + c] * w_fc1[c * 16 + r];
    hh[t] = fmaxf(s, 0.f);
  }
  __syncthreads();
  {
    int b = t >> 6, c = t & 63;
    float s = b_fc2[c];
    for (int r = 0; r < 16; ++r) s += hh[b * 16 + r] * w_fc2[r * 64 + c];
    gate[t] = 1.f / (1.f + expf(-s));
  }
  if (t < C) {
    float sc = bn_gamma[t] * rsqrtf(bn_var[t] + 1e-5f);
    bnscale[t] = sc;
    bnshift[t] = bn_beta[t] - bn_mean[t] * sc;
  }
}

// ---------------- pack W into f16 fragment-major layout ----------------
__global__ __launch_bounds__(256) void w_pack(
    const float* __restrict__ W1, const float* __restrict__ W2,
    _Float16* __restrict__ Wf1, _Float16* __restrict__ Wf2)
{
  int kk = blockIdx.x;
  const float* src = (kk < KK) ? (W1 + ((size_t)kk << 12)) : (W2 + ((size_t)(kk - KK) << 12));
  _Float16* dst = (kk < KK) ? (Wf1 + ((size_t)kk << 12)) : (Wf2 + ((size_t)(kk - KK) << 12));
  int t = threadIdx.x;
  for (int e = 0; e < 16; ++e) {
    int idx = e * 256 + t;
    int ci = idx >> 6, co = idx & 63;
    int kt = ci >> 5, i = ci & 7, lh = (ci >> 3) & 3, ct = co >> 4, col = co & 15;
    int lane = lh * 16 + col;
    dst[((kt * 4 + ct) * 64 + lane) * 8 + i] = (_Float16)src[idx];
  }
}

// ---------------- single-pass pair build (ballot, fixed per-j regions) ----------------
__global__ __launch_bounds__(256) void fill_pairs(
    const int* __restrict__ nbr, int* __restrict__ cursor,
    int* __restrict__ pairs, int N)
{
  __shared__ int wc[4][NJ];
  __shared__ int wb[4][NJ];
  int t = threadIdx.x, wv = t >> 6, lane = t & 63;
  int n = blockIdx.x * 256 + t;
  bool act = n < N;
  int v[NJ];
#pragma unroll
  for (int j = 0; j < NJ; ++j) {
    int k = j + (j >= 13);
    v[j] = act ? nbr[(size_t)k * N + n] : -1;
    unsigned long long m = __ballot(v[j] >= 0);
    if (lane == 0) wc[wv][j] = __popcll(m);
  }
  __syncthreads();
  if (t < NJ) {
    int c0 = wc[0][t], c1 = wc[1][t], c2 = wc[2][t], c3 = wc[3][t];
    int tot = c0 + c1 + c2 + c3;
    int b = tot ? atomicAdd(&cursor[t], tot) : 0;
    wb[0][t] = b; wb[1][t] = b + c0; wb[2][t] = b + c0 + c1; wb[3][t] = b + c0 + c1 + c2;
  }
  __syncthreads();
  unsigned long long lt = (1ull << lane) - 1ull;
#pragma unroll
  for (int j = 0; j < NJ; ++j) {
    bool val = v[j] >= 0;
    unsigned long long m = __ballot(val);
    if (!val) continue;
    int pos = wb[wv][j] + __popcll(m & lt);
    if (pos < KSTRIDE) {
      int slot = j * KSTRIDE + pos;
      pairs[slot * 2]     = v[j];   // src
      pairs[slot * 2 + 1] = n;      // dst
    }
  }
}

// ---------------- MFMA GEMM core (per wave: 16 rows x 64 cols x K=64) ----------------
__device__ __forceinline__ void mfma_tile(const _Float16* Af, const h8* Wb,
                                          int wv, int lane, f4 acc[4])
{
  int arow = (wv << 4) + (lane & 15);
  int koff = (lane >> 4) << 3;
  h8 a0 = *(const h8*)&Af[arow * 72 + koff];
  h8 a1 = *(const h8*)&Af[arow * 72 + 32 + koff];
#pragma unroll
  for (int ct = 0; ct < 4; ++ct) {
    h8 b0 = Wb[ct * 64 + lane];
    h8 b1 = Wb[(4 + ct) * 64 + lane];
    f4 c = {0.f, 0.f, 0.f, 0.f};
    c = __builtin_amdgcn_mfma_f32_16x16x32_f16(a0, b0, c, 0, 0, 0);
    c = __builtin_amdgcn_mfma_f32_16x16x32_f16(a1, b1, c, 0, 0, 0);
    acc[ct] = c;
  }
}

// ---------------- per-k gather-MFMA-scatter (coalesced atomics, 512 thr) ----------------
// MODE 1: conv1 scatter (A = feats * gate[bidx]), adds into h
// MODE 2: conv2 scatter (A = relu(h*bnA+bnB) on load), adds into out
template <int MODE>
__global__ __launch_bounds__(512) void scatter_k(
    const float* __restrict__ x, const _Float16* __restrict__ Wf,
    const int* __restrict__ pairs, const int* __restrict__ kcnt,
    const float* __restrict__ bnA, const float* __restrict__ bnB,
    const int* __restrict__ bidx, float* __restrict__ out)
{
  __shared__ int Sl[128], Dl[128];
  __shared__ __align__(16) char uni[128 * 68 * 4];   // union: Af f16 [128][72] | Ol f32 [128][68]
  _Float16* Af = (_Float16*)uni;
  float* Ol = (float*)uni;
  int j = blockIdx.x / SEGPK;
  int off = (blockIdx.x - j * SEGPK) << 7;
  int pCnt = min(128, kcnt[j] - off);
  if (pCnt <= 0) return;
  int k = j + (j >= 13);
  int t = threadIdx.x;
  int pBase = j * KSTRIDE + off;
  if (t < 128) {
    int s = -1, d = -1;
    if (t < pCnt) { s = pairs[(pBase + t) << 1]; d = pairs[((pBase + t) << 1) | 1]; }
    Sl[t] = s; Dl[t] = d;
  }
  __syncthreads();
  int rr = t >> 4, c4 = (t & 15) << 2;   // rr 0..31
  float4 a4, b4;
  if (MODE == 2) { a4 = *(const float4*)&bnA[c4]; b4 = *(const float4*)&bnB[c4]; }
  float4 tv[4];
#pragma unroll
  for (int it = 0; it < 4; ++it) {
    int r = (it << 5) + rr;
    float4 v = make_float4(0.f, 0.f, 0.f, 0.f);
    int src = Sl[r];
    if (src >= 0) {
      v = *(const float4*)(x + ((size_t)src << 6) + c4);
      if (MODE == 1) {
        const float* g = bnA + (bidx[src] << 6) + c4;   // bnA = gate base
        v.x *= g[0]; v.y *= g[1]; v.z *= g[2]; v.w *= g[3];
      } else {
        v.x = fmaxf(fmaf(v.x, a4.x, b4.x), 0.f);
        v.y = fmaxf(fmaf(v.y, a4.y, b4.y), 0.f);
        v.z = fmaxf(fmaf(v.z, a4.z, b4.z), 0.f);
        v.w = fmaxf(fmaf(v.w, a4.w, b4.w), 0.f);
      }
    }
    tv[it] = v;
  }
#pragma unroll
  for (int it = 0; it < 4; ++it) {
    int r = (it << 5) + rr;
    h4 hv = { (_Float16)tv[it].x, (_Float16)tv[it].y, (_Float16)tv[it].z, (_Float16)tv[it].w };
    *(h4*)&Af[r * 72 + c4] = hv;
  }
  __syncthreads();
  int wv = t >> 6, lane = t & 63;
  f4 acc[4];
  mfma_tile(Af, (const h8*)(Wf + ((size_t)k << 12)), wv, lane, acc);
  __syncthreads();   // done reading Af; reuse as Ol
  int orow0 = (wv << 4) + ((lane >> 4) << 2);
  int ocol = lane & 15;
#pragma unroll
  for (int ct = 0; ct < 4; ++ct)
#pragma unroll
    for (int rg = 0; rg < 4; ++rg)
      Ol[(orow0 + rg) * 68 + ct * 16 + ocol] = acc[ct][rg];
  __syncthreads();
  // wave wv scatters rows [wv*16, wv*16+16): one atomic instr = 64 contiguous floats
  int w0 = wv << 4;
  for (int r2 = 0; r2 < 16; ++r2) {
    int r = w0 + r2;
    int d = Dl[r];
    if (d < 0) continue;
    float val = Ol[r * 68 + lane];
    unsafeAtomicAdd(&out[((size_t)d << 6) + lane], val);
  }
}

// ---------------- dense center MFMA GEMM: direct-global A, no LDS, no barriers ----------------
// 256 thr = 4 waves, 16 rows/wave, 64 rows/block.
// MODE 0: conv1 center — A = feats*gate (f32->f16), write raw acc to h (f32)
// MODE 1: conv2 center — A = relu(h*bnA+bnB) (f32->f16), write acc + bias to out
template <int MODE>
__global__ __launch_bounds__(256) void center_epi(
    const float* __restrict__ x, const _Float16* __restrict__ Wf,
    const float* __restrict__ gate, const int* __restrict__ bidx,
    const float* __restrict__ bnA, const float* __restrict__ bnB,
    const float* __restrict__ bias, float* __restrict__ out, int N)
{
  int t = threadIdx.x, wv = t >> 6, lane = t & 63;
  int row = blockIdx.x * 64 + (wv << 4) + (lane & 15);
  int rc = min(row, N - 1);
  int koff = (lane >> 4) << 3;            // f32-element offset: 0,8,16,24
  const float* xr = x + ((size_t)rc << 6);
  float va[8], vb[8];
  *(float4*)&va[0] = *(const float4*)(xr + koff);
  *(float4*)&va[4] = *(const float4*)(xr + koff + 4);
  *(float4*)&vb[0] = *(const float4*)(xr + koff + 32);
  *(float4*)&vb[4] = *(const float4*)(xr + koff + 36);
  h8 a0, a1;
  if (MODE == 0) {
    const float* g = gate + ((size_t)(bidx[rc]) << 6);
#pragma unroll
    for (int jj = 0; jj < 8; ++jj) {
      a0[jj] = (_Float16)(va[jj] * g[koff + jj]);
      a1[jj] = (_Float16)(vb[jj] * g[koff + 32 + jj]);
    }
  } else {
#pragma unroll
    for (int jj = 0; jj < 8; ++jj) {
      a0[jj] = (_Float16)fmaxf(fmaf(va[jj], bnA[koff + jj], bnB[koff + jj]), 0.f);
      a1[jj] = (_Float16)fmaxf(fmaf(vb[jj], bnA[koff + 32 + jj], bnB[koff + 32 + jj]), 0.f);
    }
  }
  const h8* Wb = (const h8*)(Wf + ((size_t)13 << 12));
  f4 acc[4];
#pragma unroll
  for (int ct = 0; ct < 4; ++ct) {
    f4 c = {0.f, 0.f, 0.f, 0.f};
    c = __builtin_amdgcn_mfma_f32_16x16x32_f16(a0, Wb[ct * 64 + lane], c, 0, 0, 0);
    c = __builtin_amdgcn_mfma_f32_16x16x32_f16(a1, Wb[(4 + ct) * 64 + lane], c, 0, 0, 0);
    acc[ct] = c;
  }
  // C/D: row = blockbase + wv*16 + (lane>>4)*4 + rg, col = ct*16 + (lane&15)
  int obase = blockIdx.x * 64 + (wv << 4) + ((lane >> 4) << 2);
  int ocol = lane & 15;
#pragma unroll
  for (int ct = 0; ct < 4; ++ct) {
    int col = ct * 16 + ocol;
    float bv = (MODE == 1) ? bias[col] : 0.f;
#pragma unroll
    for (int rg = 0; rg < 4; ++rg) {
      int r = obase + rg;
      if (r < N) out[((size_t)r << 6) + col] = acc[ct][rg] + bv;
    }
  }
}

// ---------------- round-1 fallback (small ws) ----------------
__global__ __launch_bounds__(256) void scale_w1(
    const float* __restrict__ w1, const float* __restrict__ gate,
    float* __restrict__ w1g)
{
  int b = blockIdx.x & 3, k = blockIdx.x >> 2;
  const float* src = w1 + ((size_t)k << 12);
  float* dst = w1g + (((size_t)(b * KK + k)) << 12);
  const float* g = gate + (b << 6);
  for (int it = 0; it < 16; ++it) {
    int pos = it * 256 + threadIdx.x;
    int ci = pos >> 6;
    dst[pos] = g[ci] * src[pos];
  }
}

template <int MODE>
__global__ __launch_bounds__(256) void spconv_kernel(
    const float* __restrict__ x, const int* __restrict__ nbr,
    const int* __restrict__ bidx, const float* __restrict__ W,
    const float* __restrict__ ep_a, const float* __restrict__ ep_b,
    float* __restrict__ out, int N)
{
  int wid = (int)((blockIdx.x * 256u + threadIdx.x) >> 6);
  if (wid >= N) return;
  int lane = threadIdx.x & 63;
  int n = __builtin_amdgcn_readfirstlane(wid);
  const float* Wb = W;
  if (MODE == 0) {
    int b = __builtin_amdgcn_readfirstlane(bidx[n]);
    Wb += (size_t)b * (KK * C * C);
  }
  float acc = 0.f;
#pragma unroll 1
  for (int k = 0; k < KK; ++k) {
    int idx = __builtin_amdgcn_readfirstlane(nbr[(size_t)k * N + n]);
    if (idx < 0) continue;
    const float* xr = x + ((size_t)idx << 6);
    const float* wr = Wb + (k << 12) + lane;
#pragma unroll
    for (int ci = 0; ci < C; ++ci) acc = fmaf(xr[ci], wr[ci << 6], acc);
  }
  float r;
  if (MODE == 0) r = fmaxf(fmaf(acc, ep_a[lane], ep_b[lane]), 0.f);
  else           r = acc + ep_b[lane];
  out[((size_t)n << 6) + lane] = r;
}

extern "C" void kernel_launch(void* const* d_in, const int* in_sizes, int n_in,
                              void* d_out, int out_size, void* d_ws, size_t ws_size,
                              hipStream_t stream) {
  const float* feats   = (const float*)d_in[0];
  const int*   nbr     = (const int*)  d_in[1];
  const int*   bidx    = (const int*)  d_in[2];
  const float* w_fc1   = (const float*)d_in[3];
  const float* b_fc1   = (const float*)d_in[4];
  const float* w_fc2   = (const float*)d_in[5];
  const float* b_fc2   = (const float*)d_in[6];
  const float* w_conv1 = (const float*)d_in[7];
  const float* bn_gamma= (const float*)d_in[8];
  const float* bn_beta = (const float*)d_in[9];
  const float* bn_mean = (const float*)d_in[10];
  const float* bn_var  = (const float*)d_in[11];
  const float* w_conv2 = (const float*)d_in[12];
  const float* b_conv2 = (const float*)d_in[13];

  int N = in_sizes[0] / C;
  float* ws      = (float*)d_ws;
  float* pooled  = ws;
  float* counts  = ws + 256;
  float* gate    = ws + 260;
  float* bnscale = ws + 516;
  float* bnshift = ws + 580;
  float* out     = (float*)d_out;

  size_t need = ((size_t)H_OFF + (size_t)N * C) * 4ull;

  if (ws_size >= need) {
    int* cursor = (int*)(ws + 698);
    _Float16* Wf1 = (_Float16*)(ws + 1024);
    _Float16* Wf2 = (_Float16*)(ws + 56320);
    int* pairs  = (int*)(ws + PAIRS_OFF);
    float* h    = ws + H_OFF;

    hipLaunchKernelGGL(init_ws, dim3(4), dim3(256), 0, stream, ws);
    hipLaunchKernelGGL(pool_kernel, dim3(1024), dim3(256), 0, stream,
                       (const float4*)feats, bidx, pooled, counts, N);
    hipLaunchKernelGGL(gate_kernel, dim3(1), dim3(256), 0, stream,
                       pooled, counts, w_fc1, b_fc1, w_fc2, b_fc2,
                       bn_gamma, bn_beta, bn_mean, bn_var, gate, bnscale, bnshift);
    hipLaunchKernelGGL(w_pack, dim3(2 * KK), dim3(256), 0, stream,
                       w_conv1, w_conv2, Wf1, Wf2);
    hipLaunchKernelGGL(fill_pairs, dim3((N + 255) / 256), dim3(256), 0, stream,
                       nbr, cursor, pairs, N);
    // conv1: center writes h raw (direct-global A), then scatter adds (gated gathers)
    hipLaunchKernelGGL((center_epi<0>), dim3((N + 63) / 64), dim3(256), 0, stream,
                       feats, Wf1, gate, bidx, nullptr, nullptr, nullptr, h, N);
    hipLaunchKernelGGL((scatter_k<1>), dim3(NJ * SEGPK), dim3(512), 0, stream,
                       feats, Wf1, pairs, cursor, gate, nullptr, bidx, h);
    // conv2: BN+ReLU folded into A-loads; center writes out (+bias), scatter adds
    hipLaunchKernelGGL((center_epi<1>), dim3((N + 63) / 64), dim3(256), 0, stream,
                       h, Wf2, nullptr, nullptr, bnscale, bnshift, b_conv2, out, N);
    hipLaunchKernelGGL((scatter_k<2>), dim3(NJ * SEGPK), dim3(512), 0, stream,
                       h, Wf2, pairs, cursor, bnscale, bnshift, nullptr, out);
  } else {
    // round-1 fallback path
    float* w1g = ws + 1024;
    float* h   = ws + 1024 + BB * KK * C * C;
    hipLaunchKernelGGL(init_ws, dim3(4), dim3(256), 0, stream, ws);
    hipLaunchKernelGGL(pool_kernel, dim3(1024), dim3(256), 0, stream,
                       (const float4*)feats, bidx, pooled, counts, N);
    hipLaunchKernelGGL(gate_kernel, dim3(1), dim3(256), 0, stream,
                       pooled, counts, w_fc1, b_fc1, w_fc2, b_fc2,
                       bn_gamma, bn_beta, bn_mean, bn_var, gate, bnscale, bnshift);
    hipLaunchKernelGGL(scale_w1, dim3(KK * BB), dim3(256), 0, stream,
                       w_conv1, gate, w1g);
    hipLaunchKernelGGL((spconv_kernel<0>), dim3((N + 3) / 4), dim3(256), 0, stream,
                       feats, nbr, bidx, w1g, bnscale, bnshift, h, N);
    hipLaunchKernelGGL((spconv_kernel<1>), dim3((N + 3) / 4), dim3(256), 0, stream,
                       h, nbr, bidx, w_conv2, nullptr, b_conv2, out, N);
  }
}

// Round 19
// 729.529 us; speedup vs baseline: 1.4752x; 1.0048x over previous
//
#include <hip/hip_runtime.h>

#define C  64
#define KK 27
#define BB 4

typedef _Float16 h4 __attribute__((ext_vector_type(4)));
typedef _Float16 h8 __attribute__((ext_vector_type(8)));
typedef float    f4 __attribute__((ext_vector_type(4)));

// ===================== fast-path ws layout (float offsets) =====================
//      0 : pooled[256]
//    256 : counts[4]
//    260 : gate[256]
//    516 : bnscale[64]
//    580 : bnshift[64]
//    698 : cursor[26] (int)
//   1024 : Wf1[27*4096 halfs]  (55296 floats)
//  56320 : Wf2[27*4096 halfs]  (55296 floats)
// 114688 : pairs[NJ*KSTRIDE*2] (int)
// H_OFF  : h[N*C] (f32)
#define KSTRIDE  40960
#define SEGPK    (KSTRIDE / 128)
#define NJ       26
#define PAIRS_OFF 114688
#define H_OFF    (PAIRS_OFF + 2 * NJ * KSTRIDE)

__global__ __launch_bounds__(256) void init_ws(float* ws) {
  int t = blockIdx.x * 256 + threadIdx.x;
  if (t < 1024) ws[t] = 0.f;
}

// Grid-strided pooling: 16 threads per point row, float4 loads, shuffle+LDS reduce.
__global__ __launch_bounds__(256) void pool_kernel(
    const float4* __restrict__ x4, const int* __restrict__ bidx,
    float* __restrict__ pooled, float* __restrict__ counts, int N)
{
  int t = threadIdx.x;
  int g = t & 15;
  int rowInBlk = t >> 4;
  int lane = t & 63, wv = t >> 6;
  float4 acc[BB];
#pragma unroll
  for (int b = 0; b < BB; ++b) acc[b] = make_float4(0.f, 0.f, 0.f, 0.f);
  int cnt[BB] = {0, 0, 0, 0};
  for (int n = blockIdx.x * 16 + rowInBlk; n < N; n += gridDim.x * 16) {
    int b = bidx[n];
    float4 v = x4[((size_t)n << 4) + g];
    if (b == 0)      { acc[0].x += v.x; acc[0].y += v.y; acc[0].z += v.z; acc[0].w += v.w; }
    else if (b == 1) { acc[1].x += v.x; acc[1].y += v.y; acc[1].z += v.z; acc[1].w += v.w; }
    else if (b == 2) { acc[2].x += v.x; acc[2].y += v.y; acc[2].z += v.z; acc[2].w += v.w; }
    else             { acc[3].x += v.x; acc[3].y += v.y; acc[3].z += v.z; acc[3].w += v.w; }
    if (g == 0) {
      if (b == 0) cnt[0]++; else if (b == 1) cnt[1]++;
      else if (b == 2) cnt[2]++; else cnt[3]++;
    }
  }
#pragma unroll
  for (int b = 0; b < BB; ++b) {
    acc[b].x += __shfl_xor(acc[b].x, 16); acc[b].y += __shfl_xor(acc[b].y, 16);
    acc[b].z += __shfl_xor(acc[b].z, 16); acc[b].w += __shfl_xor(acc[b].w, 16);
    acc[b].x += __shfl_xor(acc[b].x, 32); acc[b].y += __shfl_xor(acc[b].y, 32);
    acc[b].z += __shfl_xor(acc[b].z, 32); acc[b].w += __shfl_xor(acc[b].w, 32);
    cnt[b] += __shfl_xor(cnt[b], 16);
    cnt[b] += __shfl_xor(cnt[b], 32);
  }
  __shared__ float red[4][BB][16][4];
  __shared__ int cred[4][BB];
  if (lane < 16) {
#pragma unroll
    for (int b = 0; b < BB; ++b) {
      red[wv][b][lane][0] = acc[b].x; red[wv][b][lane][1] = acc[b].y;
      red[wv][b][lane][2] = acc[b].z; red[wv][b][lane][3] = acc[b].w;
    }
    if (lane == 0) {
#pragma unroll
      for (int b = 0; b < BB; ++b) cred[wv][b] = cnt[b];
    }
  }
  __syncthreads();
  {
    int b = t >> 6, rem = t & 63;
    int gg = rem >> 2, comp = rem & 3;
    float s = red[0][b][gg][comp] + red[1][b][gg][comp] +
              red[2][b][gg][comp] + red[3][b][gg][comp];
    if (s != 0.f) atomicAdd(&pooled[b * C + (gg << 2) + comp], s);
  }
  if (t < BB) {
    int s = cred[0][t] + cred[1][t] + cred[2][t] + cred[3][t];
    if (s) atomicAdd(&counts[t], (float)s);
  }
}

__global__ __launch_bounds__(256) void gate_kernel(
    const float* __restrict__ pooled, const float* __restrict__ counts,
    const float* __restrict__ w_fc1, const float* __restrict__ b_fc1,
    const float* __restrict__ w_fc2, const float* __restrict__ b_fc2,
    const float* __restrict__ bn_gamma, const float* __restrict__ bn_beta,
    const float* __restrict__ bn_mean, const float* __restrict__ bn_var,
    float* __restrict__ gate, float* __restrict__ bnscale, float* __restrict__ bnshift)
{
  __shared__ float mean[BB * C];
  __shared__ float hh[BB * 16];
  int t = threadIdx.x;
  { int b = t >> 6; mean[t] = pooled[t] / counts[b]; }
  __syncthreads();
  if (t < BB * 16) {
    int b = t >> 4, r = t & 15;
    float s = b_fc1[r];
    for (int c = 0; c < C; ++c) s += mean[b * C + c] * w_fc1[c * 16 + r];
    hh[t] = fmaxf(s, 0.f);
  }
  __syncthreads();
  {
    int b = t >> 6, c = t & 63;
    float s = b_fc2[c];
    for (int r = 0; r < 16; ++r) s += hh[b * 16 + r] * w_fc2[r * 64 + c];
    gate[t] = 1.f / (1.f + expf(-s));
  }
  if (t < C) {
    float sc = bn_gamma[t] * rsqrtf(bn_var[t] + 1e-5f);
    bnscale[t] = sc;
    bnshift[t] = bn_beta[t] - bn_mean[t] * sc;
  }
}

// ---------------- pack W into f16 fragment-major layout ----------------
__global__ __launch_bounds__(256) void w_pack(
    const float* __restrict__ W1, const float* __restrict__ W2,
    _Float16* __restrict__ Wf1, _Float16* __restrict__ Wf2)
{
  int kk = blockIdx.x;
  const float* src = (kk < KK) ? (W1 + ((size_t)kk << 12)) : (W2 + ((size_t)(kk - KK) << 12));
  _Float16* dst = (kk < KK) ? (Wf1 + ((size_t)kk << 12)) : (Wf2 + ((size_t)(kk - KK) << 12));
  int t = threadIdx.x;
  for (int e = 0; e < 16; ++e) {
    int idx = e * 256 + t;
    int ci = idx >> 6, co = idx & 63;
    int kt = ci >> 5, i = ci & 7, lh = (ci >> 3) & 3, ct = co >> 4, col = co & 15;
    int lane = lh * 16 + col;
    dst[((kt * 4 + ct) * 64 + lane) * 8 + i] = (_Float16)src[idx];
  }
}

// ---------------- single-pass pair build (ballot, fixed per-j regions) ----------------
__global__ __launch_bounds__(256) void fill_pairs(
    const int* __restrict__ nbr, int* __restrict__ cursor,
    int* __restrict__ pairs, int N)
{
  __shared__ int wc[4][NJ];
  __shared__ int wb[4][NJ];
  int t = threadIdx.x, wv = t >> 6, lane = t & 63;
  int n = blockIdx.x * 256 + t;
  bool act = n < N;
  int v[NJ];
#pragma unroll
  for (int j = 0; j < NJ; ++j) {
    int k = j + (j >= 13);
    v[j] = act ? nbr[(size_t)k * N + n] : -1;
    unsigned long long m = __ballot(v[j] >= 0);
    if (lane == 0) wc[wv][j] = __popcll(m);
  }
  __syncthreads();
  if (t < NJ) {
    int c0 = wc[0][t], c1 = wc[1][t], c2 = wc[2][t], c3 = wc[3][t];
    int tot = c0 + c1 + c2 + c3;
    int b = tot ? atomicAdd(&cursor[t], tot) : 0;
    wb[0][t] = b; wb[1][t] = b + c0; wb[2][t] = b + c0 + c1; wb[3][t] = b + c0 + c1 + c2;
  }
  __syncthreads();
  unsigned long long lt = (1ull << lane) - 1ull;
#pragma unroll
  for (int j = 0; j < NJ; ++j) {
    bool val = v[j] >= 0;
    unsigned long long m = __ballot(val);
    if (!val) continue;
    int pos = wb[wv][j] + __popcll(m & lt);
    if (pos < KSTRIDE) {
      int slot = j * KSTRIDE + pos;
      pairs[slot * 2]     = v[j];   // src
      pairs[slot * 2 + 1] = n;      // dst
    }
  }
}

// ---------------- per-k gather-MFMA-scatter: direct-fragment atomics, 2 barriers ----------------
// MODE 1: conv1 scatter (A = feats * gate[bidx]), adds into h
// MODE 2: conv2 scatter (A = relu(h*bnA+bnB) on load), adds into out
template <int MODE>
__global__ __launch_bounds__(512) void scatter_k(
    const float* __restrict__ x, const _Float16* __restrict__ Wf,
    const int* __restrict__ pairs, const int* __restrict__ kcnt,
    const float* __restrict__ bnA, const float* __restrict__ bnB,
    const int* __restrict__ bidx, float* __restrict__ out)
{
  __shared__ int Sl[128], Dl[128];
  __shared__ __align__(16) _Float16 Af[128 * 72];   // 18KB
  int j = blockIdx.x / SEGPK;
  int off = (blockIdx.x - j * SEGPK) << 7;
  int pCnt = min(128, kcnt[j] - off);
  if (pCnt <= 0) return;
  int k = j + (j >= 13);
  int t = threadIdx.x, wv = t >> 6, lane = t & 63;
  // W-fragment loads issued before staging (LDS-independent, in flight across barrier)
  const h8* Wp = (const h8*)(Wf + ((size_t)k << 12));
  h8 wfr[8];
#pragma unroll
  for (int q = 0; q < 8; ++q) wfr[q] = Wp[q * 64 + lane];
  int pBase = j * KSTRIDE + off;
  if (t < 128) {
    int s = -1, d = -1;
    if (t < pCnt) { s = pairs[(pBase + t) << 1]; d = pairs[((pBase + t) << 1) | 1]; }
    Sl[t] = s; Dl[t] = d;
  }
  __syncthreads();
  int rr = t >> 4, c4 = (t & 15) << 2;   // rr 0..31
  float4 a4, b4;
  if (MODE == 2) { a4 = *(const float4*)&bnA[c4]; b4 = *(const float4*)&bnB[c4]; }
  float4 tv[4];
#pragma unroll
  for (int it = 0; it < 4; ++it) {
    int r = (it << 5) + rr;
    float4 v = make_float4(0.f, 0.f, 0.f, 0.f);
    int src = Sl[r];
    if (src >= 0) {
      v = *(const float4*)(x + ((size_t)src << 6) + c4);
      if (MODE == 1) {
        const float* g = bnA + (bidx[src] << 6) + c4;   // bnA = gate base
        v.x *= g[0]; v.y *= g[1]; v.z *= g[2]; v.w *= g[3];
      } else {
        v.x = fmaxf(fmaf(v.x, a4.x, b4.x), 0.f);
        v.y = fmaxf(fmaf(v.y, a4.y, b4.y), 0.f);
        v.z = fmaxf(fmaf(v.z, a4.z, b4.z), 0.f);
        v.w = fmaxf(fmaf(v.w, a4.w, b4.w), 0.f);
      }
    }
    tv[it] = v;
  }
#pragma unroll
  for (int it = 0; it < 4; ++it) {
    int r = (it << 5) + rr;
    h4 hv = { (_Float16)tv[it].x, (_Float16)tv[it].y, (_Float16)tv[it].z, (_Float16)tv[it].w };
    *(h4*)&Af[r * 72 + c4] = hv;
  }
  __syncthreads();
  int arow = (wv << 4) + (lane & 15);
  int koff = (lane >> 4) << 3;
  h8 a0 = *(const h8*)&Af[arow * 72 + koff];
  h8 a1 = *(const h8*)&Af[arow * 72 + 32 + koff];
  f4 acc[4];
#pragma unroll
  for (int ct = 0; ct < 4; ++ct) {
    f4 c = {0.f, 0.f, 0.f, 0.f};
    c = __builtin_amdgcn_mfma_f32_16x16x32_f16(a0, wfr[ct], c, 0, 0, 0);
    c = __builtin_amdgcn_mfma_f32_16x16x32_f16(a1, wfr[4 + ct], c, 0, 0, 0);
    acc[ct] = c;
  }
  // direct-fragment atomics: for fixed (ct,rg), lanes 0-15 = one fully-dirty 64B line,
  // 4 lane-groups = 4 rows -> identical line coverage to the old Ol roundtrip.
  int rbase = (wv << 4) + ((lane >> 4) << 2);
  int ocol = lane & 15;
  int dr[4];
#pragma unroll
  for (int rg = 0; rg < 4; ++rg) dr[rg] = Dl[rbase + rg];
#pragma unroll
  for (int ct = 0; ct < 4; ++ct)
#pragma unroll
    for (int rg = 0; rg < 4; ++rg) {
      int d = dr[rg];
      if (d >= 0)
        unsafeAtomicAdd(&out[((size_t)d << 6) + ct * 16 + ocol], acc[ct][rg]);
    }
}

// ---------------- dense center MFMA GEMM: direct-global A, no LDS, no barriers ----------------
// MODE 0: conv1 center — A = feats*gate (f32->f16), write raw acc to h (f32)
// MODE 1: conv2 center — A = relu(h*bnA+bnB) (f32->f16), write acc + bias to out
template <int MODE>
__global__ __launch_bounds__(256) void center_epi(
    const float* __restrict__ x, const _Float16* __restrict__ Wf,
    const float* __restrict__ gate, const int* __restrict__ bidx,
    const float* __restrict__ bnA, const float* __restrict__ bnB,
    const float* __restrict__ bias, float* __restrict__ out, int N)
{
  int t = threadIdx.x, wv = t >> 6, lane = t & 63;
  int row = blockIdx.x * 64 + (wv << 4) + (lane & 15);
  int rc = min(row, N - 1);
  int koff = (lane >> 4) << 3;            // f32-element offset: 0,8,16,24
  const float* xr = x + ((size_t)rc << 6);
  float va[8], vb[8];
  *(float4*)&va[0] = *(const float4*)(xr + koff);
  *(float4*)&va[4] = *(const float4*)(xr + koff + 4);
  *(float4*)&vb[0] = *(const float4*)(xr + koff + 32);
  *(float4*)&vb[4] = *(const float4*)(xr + koff + 36);
  h8 a0, a1;
  if (MODE == 0) {
    const float* g = gate + ((size_t)(bidx[rc]) << 6);
#pragma unroll
    for (int jj = 0; jj < 8; ++jj) {
      a0[jj] = (_Float16)(va[jj] * g[koff + jj]);
      a1[jj] = (_Float16)(vb[jj] * g[koff + 32 + jj]);
    }
  } else {
#pragma unroll
    for (int jj = 0; jj < 8; ++jj) {
      a0[jj] = (_Float16)fmaxf(fmaf(va[jj], bnA[koff + jj], bnB[koff + jj]), 0.f);
      a1[jj] = (_Float16)fmaxf(fmaf(vb[jj], bnA[koff + 32 + jj], bnB[koff + 32 + jj]), 0.f);
    }
  }
  const h8* Wb = (const h8*)(Wf + ((size_t)13 << 12));
  f4 acc[4];
#pragma unroll
  for (int ct = 0; ct < 4; ++ct) {
    f4 c = {0.f, 0.f, 0.f, 0.f};
    c = __builtin_amdgcn_mfma_f32_16x16x32_f16(a0, Wb[ct * 64 + lane], c, 0, 0, 0);
    c = __builtin_amdgcn_mfma_f32_16x16x32_f16(a1, Wb[(4 + ct) * 64 + lane], c, 0, 0, 0);
    acc[ct] = c;
  }
  int obase = blockIdx.x * 64 + (wv << 4) + ((lane >> 4) << 2);
  int ocol = lane & 15;
#pragma unroll
  for (int ct = 0; ct < 4; ++ct) {
    int col = ct * 16 + ocol;
    float bv = (MODE == 1) ? bias[col] : 0.f;
#pragma unroll
    for (int rg = 0; rg < 4; ++rg) {
      int r = obase + rg;
      if (r < N) out[((size_t)r << 6) + col] = acc[ct][rg] + bv;
    }
  }
}

// ---------------- round-1 fallback (small ws) ----------------
__global__ __launch_bounds__(256) void scale_w1(
    const float* __restrict__ w1, const float* __restrict__ gate,
    float* __restrict__ w1g)
{
  int b = blockIdx.x & 3, k = blockIdx.x >> 2;
  const float* src = w1 + ((size_t)k << 12);
  float* dst = w1g + (((size_t)(b * KK + k)) << 12);
  const float* g = gate + (b << 6);
  for (int it = 0; it < 16; ++it) {
    int pos = it * 256 + threadIdx.x;
    int ci = pos >> 6;
    dst[pos] = g[ci] * src[pos];
  }
}

template <int MODE>
__global__ __launch_bounds__(256) void spconv_kernel(
    const float* __restrict__ x, const int* __restrict__ nbr,
    const int* __restrict__ bidx, const float* __restrict__ W,
    const float* __restrict__ ep_a, const float* __restrict__ ep_b,
    float* __restrict__ out, int N)
{
  int wid = (int)((blockIdx.x * 256u + threadIdx.x) >> 6);
  if (wid >= N) return;
  int lane = threadIdx.x & 63;
  int n = __builtin_amdgcn_readfirstlane(wid);
  const float* Wb = W;
  if (MODE == 0) {
    int b = __builtin_amdgcn_readfirstlane(bidx[n]);
    Wb += (size_t)b * (KK * C * C);
  }
  float acc = 0.f;
#pragma unroll 1
  for (int k = 0; k < KK; ++k) {
    int idx = __builtin_amdgcn_readfirstlane(nbr[(size_t)k * N + n]);
    if (idx < 0) continue;
    const float* xr = x + ((size_t)idx << 6);
    const float* wr = Wb + (k << 12) + lane;
#pragma unroll
    for (int ci = 0; ci < C; ++ci) acc = fmaf(xr[ci], wr[ci << 6], acc);
  }
  float r;
  if (MODE == 0) r = fmaxf(fmaf(acc, ep_a[lane], ep_b[lane]), 0.f);
  else           r = acc + ep_b[lane];
  out[((size_t)n << 6) + lane] = r;
}

extern "C" void kernel_launch(void* const* d_in, const int* in_sizes, int n_in,
                              void* d_out, int out_size, void* d_ws, size_t ws_size,
                              hipStream_t stream) {
  const float* feats   = (const float*)d_in[0];
  const int*   nbr     = (const int*)  d_in[1];
  const int*   bidx    = (const int*)  d_in[2];
  const float* w_fc1   = (const float*)d_in[3];
  const float* b_fc1   = (const float*)d_in[4];
  const float* w_fc2   = (const float*)d_in[5];
  const float* b_fc2   = (const float*)d_in[6];
  const float* w_conv1 = (const float*)d_in[7];
  const float* bn_gamma= (const float*)d_in[8];
  const float* bn_beta = (const float*)d_in[9];
  const float* bn_mean = (const float*)d_in[10];
  const float* bn_var  = (const float*)d_in[11];
  const float* w_conv2 = (const float*)d_in[12];
  const float* b_conv2 = (const float*)d_in[13];

  int N = in_sizes[0] / C;
  float* ws      = (float*)d_ws;
  float* pooled  = ws;
  float* counts  = ws + 256;
  float* gate    = ws + 260;
  float* bnscale = ws + 516;
  float* bnshift = ws + 580;
  float* out     = (float*)d_out;

  size_t need = ((size_t)H_OFF + (size_t)N * C) * 4ull;

  if (ws_size >= need) {
    int* cursor = (int*)(ws + 698);
    _Float16* Wf1 = (_Float16*)(ws + 1024);
    _Float16* Wf2 = (_Float16*)(ws + 56320);
    int* pairs  = (int*)(ws + PAIRS_OFF);
    float* h    = ws + H_OFF;

    hipLaunchKernelGGL(init_ws, dim3(4), dim3(256), 0, stream, ws);
    hipLaunchKernelGGL(pool_kernel, dim3(1024), dim3(256), 0, stream,
                       (const float4*)feats, bidx, pooled, counts, N);
    hipLaunchKernelGGL(gate_kernel, dim3(1), dim3(256), 0, stream,
                       pooled, counts, w_fc1, b_fc1, w_fc2, b_fc2,
                       bn_gamma, bn_beta, bn_mean, bn_var, gate, bnscale, bnshift);
    hipLaunchKernelGGL(w_pack, dim3(2 * KK), dim3(256), 0, stream,
                       w_conv1, w_conv2, Wf1, Wf2);
    hipLaunchKernelGGL(fill_pairs, dim3((N + 255) / 256), dim3(256), 0, stream,
                       nbr, cursor, pairs, N);
    // conv1: center writes h raw (direct-global A), then scatter adds (gated gathers)
    hipLaunchKernelGGL((center_epi<0>), dim3((N + 63) / 64), dim3(256), 0, stream,
                       feats, Wf1, gate, bidx, nullptr, nullptr, nullptr, h, N);
    hipLaunchKernelGGL((scatter_k<1>), dim3(NJ * SEGPK), dim3(512), 0, stream,
                       feats, Wf1, pairs, cursor, gate, nullptr, bidx, h);
    // conv2: BN+ReLU folded into A-loads; center writes out (+bias), scatter adds
    hipLaunchKernelGGL((center_epi<1>), dim3((N + 63) / 64), dim3(256), 0, stream,
                       h, Wf2, nullptr, nullptr, bnscale, bnshift, b_conv2, out, N);
    hipLaunchKernelGGL((scatter_k<2>), dim3(NJ * SEGPK), dim3(512), 0, stream,
                       h, Wf2, pairs, cursor, bnscale, bnshift, nullptr, out);
  } else {
    // round-1 fallback path
    float* w1g = ws + 1024;
    float* h   = ws + 1024 + BB * KK * C * C;
    hipLaunchKernelGGL(init_ws, dim3(4), dim3(256), 0, stream, ws);
    hipLaunchKernelGGL(pool_kernel, dim3(1024), dim3(256), 0, stream,
                       (const float4*)feats, bidx, pooled, counts, N);
    hipLaunchKernelGGL(gate_kernel, dim3(1), dim3(256), 0, stream,
                       pooled, counts, w_fc1, b_fc1, w_fc2, b_fc2,
                       bn_gamma, bn_beta, bn_mean, bn_var, gate, bnscale, bnshift);
    hipLaunchKernelGGL(scale_w1, dim3(KK * BB), dim3(256), 0, stream,
                       w_conv1, gate, w1g);
    hipLaunchKernelGGL((spconv_kernel<0>), dim3((N + 3) / 4), dim3(256), 0, stream,
                       feats, nbr, bidx, w1g, bnscale, bnshift, h, N);
    hipLaunchKernelGGL((spconv_kernel<1>), dim3((N + 3) / 4), dim3(256), 0, stream,
                       h, nbr, bidx, w_conv2, nullptr, b_conv2, out, N);
  }
}

// Round 20
// 727.550 us; speedup vs baseline: 1.4792x; 1.0027x over previous
//
#include <hip/hip_runtime.h>

#define C  64
#define KK 27
#define BB 4

typedef _Float16 h4 __attribute__((ext_vector_type(4)));
typedef _Float16 h8 __attribute__((ext_vector_type(8)));
typedef float    f4 __attribute__((ext_vector_type(4)));
typedef float    v2f __attribute__((ext_vector_type(2)));

#if defined(__has_builtin)
#if __has_builtin(__builtin_amdgcn_global_atomic_fadd_v2f32)
#define HAVE_PK_F32 1
#endif
#endif
#ifndef HAVE_PK_F32
#define HAVE_PK_F32 0
#endif

// ===================== fast-path ws layout (float offsets) =====================
//      0 : pooled[256]
//    256 : counts[4]
//    260 : gate[256]
//    516 : bnscale[64]
//    580 : bnshift[64]
//    698 : cursor[26] (int)
//   1024 : Wf1[27*4096 halfs]  (55296 floats)
//  56320 : Wf2[27*4096 halfs]  (55296 floats)
// 114688 : pairs[NJ*KSTRIDE*2] (int)
// H_OFF  : h[N*C] (f32)
#define KSTRIDE  40960
#define SEGPK    (KSTRIDE / 128)
#define NJ       26
#define PAIRS_OFF 114688
#define H_OFF    (PAIRS_OFF + 2 * NJ * KSTRIDE)

__global__ __launch_bounds__(256) void init_ws(float* ws) {
  int t = blockIdx.x * 256 + threadIdx.x;
  if (t < 1024) ws[t] = 0.f;
}

// Grid-strided pooling: 16 threads per point row, float4 loads, shuffle+LDS reduce.
__global__ __launch_bounds__(256) void pool_kernel(
    const float4* __restrict__ x4, const int* __restrict__ bidx,
    float* __restrict__ pooled, float* __restrict__ counts, int N)
{
  int t = threadIdx.x;
  int g = t & 15;
  int rowInBlk = t >> 4;
  int lane = t & 63, wv = t >> 6;
  float4 acc[BB];
#pragma unroll
  for (int b = 0; b < BB; ++b) acc[b] = make_float4(0.f, 0.f, 0.f, 0.f);
  int cnt[BB] = {0, 0, 0, 0};
  for (int n = blockIdx.x * 16 + rowInBlk; n < N; n += gridDim.x * 16) {
    int b = bidx[n];
    float4 v = x4[((size_t)n << 4) + g];
    if (b == 0)      { acc[0].x += v.x; acc[0].y += v.y; acc[0].z += v.z; acc[0].w += v.w; }
    else if (b == 1) { acc[1].x += v.x; acc[1].y += v.y; acc[1].z += v.z; acc[1].w += v.w; }
    else if (b == 2) { acc[2].x += v.x; acc[2].y += v.y; acc[2].z += v.z; acc[2].w += v.w; }
    else             { acc[3].x += v.x; acc[3].y += v.y; acc[3].z += v.z; acc[3].w += v.w; }
    if (g == 0) {
      if (b == 0) cnt[0]++; else if (b == 1) cnt[1]++;
      else if (b == 2) cnt[2]++; else cnt[3]++;
    }
  }
#pragma unroll
  for (int b = 0; b < BB; ++b) {
    acc[b].x += __shfl_xor(acc[b].x, 16); acc[b].y += __shfl_xor(acc[b].y, 16);
    acc[b].z += __shfl_xor(acc[b].z, 16); acc[b].w += __shfl_xor(acc[b].w, 16);
    acc[b].x += __shfl_xor(acc[b].x, 32); acc[b].y += __shfl_xor(acc[b].y, 32);
    acc[b].z += __shfl_xor(acc[b].z, 32); acc[b].w += __shfl_xor(acc[b].w, 32);
    cnt[b] += __shfl_xor(cnt[b], 16);
    cnt[b] += __shfl_xor(cnt[b], 32);
  }
  __shared__ float red[4][BB][16][4];
  __shared__ int cred[4][BB];
  if (lane < 16) {
#pragma unroll
    for (int b = 0; b < BB; ++b) {
      red[wv][b][lane][0] = acc[b].x; red[wv][b][lane][1] = acc[b].y;
      red[wv][b][lane][2] = acc[b].z; red[wv][b][lane][3] = acc[b].w;
    }
    if (lane == 0) {
#pragma unroll
      for (int b = 0; b < BB; ++b) cred[wv][b] = cnt[b];
    }
  }
  __syncthreads();
  {
    int b = t >> 6, rem = t & 63;
    int gg = rem >> 2, comp = rem & 3;
    float s = red[0][b][gg][comp] + red[1][b][gg][comp] +
              red[2][b][gg][comp] + red[3][b][gg][comp];
    if (s != 0.f) atomicAdd(&pooled[b * C + (gg << 2) + comp], s);
  }
  if (t < BB) {
    int s = cred[0][t] + cred[1][t] + cred[2][t] + cred[3][t];
    if (s) atomicAdd(&counts[t], (float)s);
  }
}

__global__ __launch_bounds__(256) void gate_kernel(
    const float* __restrict__ pooled, const float* __restrict__ counts,
    const float* __restrict__ w_fc1, const float* __restrict__ b_fc1,
    const float* __restrict__ w_fc2, const float* __restrict__ b_fc2,
    const float* __restrict__ bn_gamma, const float* __restrict__ bn_beta,
    const float* __restrict__ bn_mean, const float* __restrict__ bn_var,
    float* __restrict__ gate, float* __restrict__ bnscale, float* __restrict__ bnshift)
{
  __shared__ float mean[BB * C];
  __shared__ float hh[BB * 16];
  int t = threadIdx.x;
  { int b = t >> 6; mean[t] = pooled[t] / counts[b]; }
  __syncthreads();
  if (t < BB * 16) {
    int b = t >> 4, r = t & 15;
    float s = b_fc1[r];
    for (int c = 0; c < C; ++c) s += mean[b * C + c] * w_fc1[c * 16 + r];
    hh[t] = fmaxf(s, 0.f);
  }
  __syncthreads();
  {
    int b = t >> 6, c = t & 63;
    float s = b_fc2[c];
    for (int r = 0; r < 16; ++r) s += hh[b * 16 + r] * w_fc2[r * 64 + c];
    gate[t] = 1.f / (1.f + expf(-s));
  }
  if (t < C) {
    float sc = bn_gamma[t] * rsqrtf(bn_var[t] + 1e-5f);
    bnscale[t] = sc;
    bnshift[t] = bn_beta[t] - bn_mean[t] * sc;
  }
}

// ---------------- pack W into f16 fragment-major layout ----------------
__global__ __launch_bounds__(256) void w_pack(
    const float* __restrict__ W1, const float* __restrict__ W2,
    _Float16* __restrict__ Wf1, _Float16* __restrict__ Wf2)
{
  int kk = blockIdx.x;
  const float* src = (kk < KK) ? (W1 + ((size_t)kk << 12)) : (W2 + ((size_t)(kk - KK) << 12));
  _Float16* dst = (kk < KK) ? (Wf1 + ((size_t)kk << 12)) : (Wf2 + ((size_t)(kk - KK) << 12));
  int t = threadIdx.x;
  for (int e = 0; e < 16; ++e) {
    int idx = e * 256 + t;
    int ci = idx >> 6, co = idx & 63;
    int kt = ci >> 5, i = ci & 7, lh = (ci >> 3) & 3, ct = co >> 4, col = co & 15;
    int lane = lh * 16 + col;
    dst[((kt * 4 + ct) * 64 + lane) * 8 + i] = (_Float16)src[idx];
  }
}

// ---------------- single-pass pair build (ballot, fixed per-j regions) ----------------
__global__ __launch_bounds__(256) void fill_pairs(
    const int* __restrict__ nbr, int* __restrict__ cursor,
    int* __restrict__ pairs, int N)
{
  __shared__ int wc[4][NJ];
  __shared__ int wb[4][NJ];
  int t = threadIdx.x, wv = t >> 6, lane = t & 63;
  int n = blockIdx.x * 256 + t;
  bool act = n < N;
  int v[NJ];
#pragma unroll
  for (int j = 0; j < NJ; ++j) {
    int k = j + (j >= 13);
    v[j] = act ? nbr[(size_t)k * N + n] : -1;
    unsigned long long m = __ballot(v[j] >= 0);
    if (lane == 0) wc[wv][j] = __popcll(m);
  }
  __syncthreads();
  if (t < NJ) {
    int c0 = wc[0][t], c1 = wc[1][t], c2 = wc[2][t], c3 = wc[3][t];
    int tot = c0 + c1 + c2 + c3;
    int b = tot ? atomicAdd(&cursor[t], tot) : 0;
    wb[0][t] = b; wb[1][t] = b + c0; wb[2][t] = b + c0 + c1; wb[3][t] = b + c0 + c1 + c2;
  }
  __syncthreads();
  unsigned long long lt = (1ull << lane) - 1ull;
#pragma unroll
  for (int j = 0; j < NJ; ++j) {
    bool val = v[j] >= 0;
    unsigned long long m = __ballot(val);
    if (!val) continue;
    int pos = wb[wv][j] + __popcll(m & lt);
    if (pos < KSTRIDE) {
      int slot = j * KSTRIDE + pos;
      pairs[slot * 2]     = v[j];   // src
      pairs[slot * 2 + 1] = n;      // dst
    }
  }
}

// ---------------- per-k gather-MFMA-scatter: packed-f32 atomics ----------------
// MODE 1: conv1 scatter (A = feats * gate[bidx]), adds into h
// MODE 2: conv2 scatter (A = relu(h*bnA+bnB) on load), adds into out
template <int MODE>
__global__ __launch_bounds__(512) void scatter_k(
    const float* __restrict__ x, const _Float16* __restrict__ Wf,
    const int* __restrict__ pairs, const int* __restrict__ kcnt,
    const float* __restrict__ bnA, const float* __restrict__ bnB,
    const int* __restrict__ bidx, float* __restrict__ out)
{
  __shared__ int Sl[128], Dl[128];
  __shared__ __align__(16) _Float16 Af[128 * 72];   // 18KB
  int j = blockIdx.x / SEGPK;
  int off = (blockIdx.x - j * SEGPK) << 7;
  int pCnt = min(128, kcnt[j] - off);
  if (pCnt <= 0) return;
  int k = j + (j >= 13);
  int t = threadIdx.x, wv = t >> 6, lane = t & 63;
  // W-fragment loads issued before staging (LDS-independent, in flight across barrier)
  const h8* Wp = (const h8*)(Wf + ((size_t)k << 12));
  h8 wfr[8];
#pragma unroll
  for (int q = 0; q < 8; ++q) wfr[q] = Wp[q * 64 + lane];
  int pBase = j * KSTRIDE + off;
  if (t < 128) {
    int s = -1, d = -1;
    if (t < pCnt) { s = pairs[(pBase + t) << 1]; d = pairs[((pBase + t) << 1) | 1]; }
    Sl[t] = s; Dl[t] = d;
  }
  __syncthreads();
  int rr = t >> 4, c4 = (t & 15) << 2;   // rr 0..31
  float4 a4, b4;
  if (MODE == 2) { a4 = *(const float4*)&bnA[c4]; b4 = *(const float4*)&bnB[c4]; }
  float4 tv[4];
#pragma unroll
  for (int it = 0; it < 4; ++it) {
    int r = (it << 5) + rr;
    float4 v = make_float4(0.f, 0.f, 0.f, 0.f);
    int src = Sl[r];
    if (src >= 0) {
      v = *(const float4*)(x + ((size_t)src << 6) + c4);
      if (MODE == 1) {
        const float* g = bnA + (bidx[src] << 6) + c4;   // bnA = gate base
        v.x *= g[0]; v.y *= g[1]; v.z *= g[2]; v.w *= g[3];
      } else {
        v.x = fmaxf(fmaf(v.x, a4.x, b4.x), 0.f);
        v.y = fmaxf(fmaf(v.y, a4.y, b4.y), 0.f);
        v.z = fmaxf(fmaf(v.z, a4.z, b4.z), 0.f);
        v.w = fmaxf(fmaf(v.w, a4.w, b4.w), 0.f);
      }
    }
    tv[it] = v;
  }
#pragma unroll
  for (int it = 0; it < 4; ++it) {
    int r = (it << 5) + rr;
    h4 hv = { (_Float16)tv[it].x, (_Float16)tv[it].y, (_Float16)tv[it].z, (_Float16)tv[it].w };
    *(h4*)&Af[r * 72 + c4] = hv;
  }
  __syncthreads();
  int arow = (wv << 4) + (lane & 15);
  int koff = (lane >> 4) << 3;
  h8 a0 = *(const h8*)&Af[arow * 72 + koff];
  h8 a1 = *(const h8*)&Af[arow * 72 + 32 + koff];
  f4 acc[4];
#pragma unroll
  for (int ct = 0; ct < 4; ++ct) {
    f4 c = {0.f, 0.f, 0.f, 0.f};
    c = __builtin_amdgcn_mfma_f32_16x16x32_f16(a0, wfr[ct], c, 0, 0, 0);
    c = __builtin_amdgcn_mfma_f32_16x16x32_f16(a1, wfr[4 + ct], c, 0, 0, 0);
    acc[ct] = c;
  }
  int rbase = (wv << 4) + ((lane >> 4) << 2);
  int ocol = lane & 15;
  int dr[4];
#pragma unroll
  for (int rg = 0; rg < 4; ++rg) dr[rg] = Dl[rbase + rg];
#if HAVE_PK_F32
  // Packed-f32 atomics: cols c,c+1 live in adjacent lanes for fixed (ct,rg);
  // shfl_xor(1) pairs them, even lanes issue one 8B GLOBAL_ATOMIC_PK_ADD_F32.
  bool evenl = (lane & 1) == 0;
#pragma unroll
  for (int ct = 0; ct < 4; ++ct)
#pragma unroll
    for (int rg = 0; rg < 4; ++rg) {
      float v = acc[ct][rg];
      float vn = __shfl_xor(v, 1);
      int d = dr[rg];
      if (evenl && d >= 0) {
        v2f pv = {v, vn};
        typedef __attribute__((address_space(1))) v2f gv2f;
        __builtin_amdgcn_global_atomic_fadd_v2f32(
            (gv2f*)(out + ((size_t)d << 6) + ct * 16 + ocol), pv);
      }
    }
#else
#pragma unroll
  for (int ct = 0; ct < 4; ++ct)
#pragma unroll
    for (int rg = 0; rg < 4; ++rg) {
      int d = dr[rg];
      if (d >= 0)
        unsafeAtomicAdd(&out[((size_t)d << 6) + ct * 16 + ocol], acc[ct][rg]);
    }
#endif
}

// ---------------- dense center MFMA GEMM: direct-global A, no LDS, no barriers ----------------
// MODE 0: conv1 center — A = feats*gate (f32->f16), write raw acc to h (f32)
// MODE 1: conv2 center — A = relu(h*bnA+bnB) (f32->f16), write acc + bias to out
template <int MODE>
__global__ __launch_bounds__(256) void center_epi(
    const float* __restrict__ x, const _Float16* __restrict__ Wf,
    const float* __restrict__ gate, const int* __restrict__ bidx,
    const float* __restrict__ bnA, const float* __restrict__ bnB,
    const float* __restrict__ bias, float* __restrict__ out, int N)
{
  int t = threadIdx.x, wv = t >> 6, lane = t & 63;
  int row = blockIdx.x * 64 + (wv << 4) + (lane & 15);
  int rc = min(row, N - 1);
  int koff = (lane >> 4) << 3;            // f32-element offset: 0,8,16,24
  const float* xr = x + ((size_t)rc << 6);
  float va[8], vb[8];
  *(float4*)&va[0] = *(const float4*)(xr + koff);
  *(float4*)&va[4] = *(const float4*)(xr + koff + 4);
  *(float4*)&vb[0] = *(const float4*)(xr + koff + 32);
  *(float4*)&vb[4] = *(const float4*)(xr + koff + 36);
  h8 a0, a1;
  if (MODE == 0) {
    const float* g = gate + ((size_t)(bidx[rc]) << 6);
#pragma unroll
    for (int jj = 0; jj < 8; ++jj) {
      a0[jj] = (_Float16)(va[jj] * g[koff + jj]);
      a1[jj] = (_Float16)(vb[jj] * g[koff + 32 + jj]);
    }
  } else {
#pragma unroll
    for (int jj = 0; jj < 8; ++jj) {
      a0[jj] = (_Float16)fmaxf(fmaf(va[jj], bnA[koff + jj], bnB[koff + jj]), 0.f);
      a1[jj] = (_Float16)fmaxf(fmaf(vb[jj], bnA[koff + 32 + jj], bnB[koff + 32 + jj]), 0.f);
    }
  }
  const h8* Wb = (const h8*)(Wf + ((size_t)13 << 12));
  f4 acc[4];
#pragma unroll
  for (int ct = 0; ct < 4; ++ct) {
    f4 c = {0.f, 0.f, 0.f, 0.f};
    c = __builtin_amdgcn_mfma_f32_16x16x32_f16(a0, Wb[ct * 64 + lane], c, 0, 0, 0);
    c = __builtin_amdgcn_mfma_f32_16x16x32_f16(a1, Wb[(4 + ct) * 64 + lane], c, 0, 0, 0);
    acc[ct] = c;
  }
  int obase = blockIdx.x * 64 + (wv << 4) + ((lane >> 4) << 2);
  int ocol = lane & 15;
#pragma unroll
  for (int ct = 0; ct < 4; ++ct) {
    int col = ct * 16 + ocol;
    float bv = (MODE == 1) ? bias[col] : 0.f;
#pragma unroll
    for (int rg = 0; rg < 4; ++rg) {
      int r = obase + rg;
      if (r < N) out[((size_t)r << 6) + col] = acc[ct][rg] + bv;
    }
  }
}

// ---------------- round-1 fallback (small ws) ----------------
__global__ __launch_bounds__(256) void scale_w1(
    const float* __restrict__ w1, const float* __restrict__ gate,
    float* __restrict__ w1g)
{
  int b = blockIdx.x & 3, k = blockIdx.x >> 2;
  const float* src = w1 + ((size_t)k << 12);
  float* dst = w1g + (((size_t)(b * KK + k)) << 12);
  const float* g = gate + (b << 6);
  for (int it = 0; it < 16; ++it) {
    int pos = it * 256 + threadIdx.x;
    int ci = pos >> 6;
    dst[pos] = g[ci] * src[pos];
  }
}

template <int MODE>
__global__ __launch_bounds__(256) void spconv_kernel(
    const float* __restrict__ x, const int* __restrict__ nbr,
    const int* __restrict__ bidx, const float* __restrict__ W,
    const float* __restrict__ ep_a, const float* __restrict__ ep_b,
    float* __restrict__ out, int N)
{
  int wid = (int)((blockIdx.x * 256u + threadIdx.x) >> 6);
  if (wid >= N) return;
  int lane = threadIdx.x & 63;
  int n = __builtin_amdgcn_readfirstlane(wid);
  const float* Wb = W;
  if (MODE == 0) {
    int b = __builtin_amdgcn_readfirstlane(bidx[n]);
    Wb += (size_t)b * (KK * C * C);
  }
  float acc = 0.f;
#pragma unroll 1
  for (int k = 0; k < KK; ++k) {
    int idx = __builtin_amdgcn_readfirstlane(nbr[(size_t)k * N + n]);
    if (idx < 0) continue;
    const float* xr = x + ((size_t)idx << 6);
    const float* wr = Wb + (k << 12) + lane;
#pragma unroll
    for (int ci = 0; ci < C; ++ci) acc = fmaf(xr[ci], wr[ci << 6], acc);
  }
  float r;
  if (MODE == 0) r = fmaxf(fmaf(acc, ep_a[lane], ep_b[lane]), 0.f);
  else           r = acc + ep_b[lane];
  out[((size_t)n << 6) + lane] = r;
}

extern "C" void kernel_launch(void* const* d_in, const int* in_sizes, int n_in,
                              void* d_out, int out_size, void* d_ws, size_t ws_size,
                              hipStream_t stream) {
  const float* feats   = (const float*)d_in[0];
  const int*   nbr     = (const int*)  d_in[1];
  const int*   bidx    = (const int*)  d_in[2];
  const float* w_fc1   = (const float*)d_in[3];
  const float* b_fc1   = (const float*)d_in[4];
  const float* w_fc2   = (const float*)d_in[5];
  const float* b_fc2   = (const float*)d_in[6];
  const float* w_conv1 = (const float*)d_in[7];
  const float* bn_gamma= (const float*)d_in[8];
  const float* bn_beta = (const float*)d_in[9];
  const float* bn_mean = (const float*)d_in[10];
  const float* bn_var  = (const float*)d_in[11];
  const float* w_conv2 = (const float*)d_in[12];
  const float* b_conv2 = (const float*)d_in[13];

  int N = in_sizes[0] / C;
  float* ws      = (float*)d_ws;
  float* pooled  = ws;
  float* counts  = ws + 256;
  float* gate    = ws + 260;
  float* bnscale = ws + 516;
  float* bnshift = ws + 580;
  float* out     = (float*)d_out;

  size_t need = ((size_t)H_OFF + (size_t)N * C) * 4ull;

  if (ws_size >= need) {
    int* cursor = (int*)(ws + 698);
    _Float16* Wf1 = (_Float16*)(ws + 1024);
    _Float16* Wf2 = (_Float16*)(ws + 56320);
    int* pairs  = (int*)(ws + PAIRS_OFF);
    float* h    = ws + H_OFF;

    hipLaunchKernelGGL(init_ws, dim3(4), dim3(256), 0, stream, ws);
    hipLaunchKernelGGL(pool_kernel, dim3(1024), dim3(256), 0, stream,
                       (const float4*)feats, bidx, pooled, counts, N);
    hipLaunchKernelGGL(gate_kernel, dim3(1), dim3(256), 0, stream,
                       pooled, counts, w_fc1, b_fc1, w_fc2, b_fc2,
                       bn_gamma, bn_beta, bn_mean, bn_var, gate, bnscale, bnshift);
    hipLaunchKernelGGL(w_pack, dim3(2 * KK), dim3(256), 0, stream,
                       w_conv1, w_conv2, Wf1, Wf2);
    hipLaunchKernelGGL(fill_pairs, dim3((N + 255) / 256), dim3(256), 0, stream,
                       nbr, cursor, pairs, N);
    // conv1: center writes h raw (direct-global A), then scatter adds (gated gathers)
    hipLaunchKernelGGL((center_epi<0>), dim3((N + 63) / 64), dim3(256), 0, stream,
                       feats, Wf1, gate, bidx, nullptr, nullptr, nullptr, h, N);
    hipLaunchKernelGGL((scatter_k<1>), dim3(NJ * SEGPK), dim3(512), 0, stream,
                       feats, Wf1, pairs, cursor, gate, nullptr, bidx, h);
    // conv2: BN+ReLU folded into A-loads; center writes out (+bias), scatter adds
    hipLaunchKernelGGL((center_epi<1>), dim3((N + 63) / 64), dim3(256), 0, stream,
                       h, Wf2, nullptr, nullptr, bnscale, bnshift, b_conv2, out, N);
    hipLaunchKernelGGL((scatter_k<2>), dim3(NJ * SEGPK), dim3(512), 0, stream,
                       h, Wf2, pairs, cursor, bnscale, bnshift, nullptr, out);
  } else {
    // round-1 fallback path
    float* w1g = ws + 1024;
    float* h   = ws + 1024 + BB * KK * C * C;
    hipLaunchKernelGGL(init_ws, dim3(4), dim3(256), 0, stream, ws);
    hipLaunchKernelGGL(pool_kernel, dim3(1024), dim3(256), 0, stream,
                       (const float4*)feats, bidx, pooled, counts, N);
    hipLaunchKernelGGL(gate_kernel, dim3(1), dim3(256), 0, stream,
                       pooled, counts, w_fc1, b_fc1, w_fc2, b_fc2,
                       bn_gamma, bn_beta, bn_mean, bn_var, gate, bnscale, bnshift);
    hipLaunchKernelGGL(scale_w1, dim3(KK * BB), dim3(256), 0, stream,
                       w_conv1, gate, w1g);
    hipLaunchKernelGGL((spconv_kernel<0>), dim3((N + 3) / 4), dim3(256), 0, stream,
                       feats, nbr, bidx, w1g, bnscale, bnshift, h, N);
    hipLaunchKernelGGL((spconv_kernel<1>), dim3((N + 3) / 4), dim3(256), 0, stream,
                       h, nbr, bidx, w_conv2, nullptr, b_conv2, out, N);
  }
}